// Round 3
// baseline (1498.913 us; speedup 1.0000x reference)
//
#include <hip/hip_runtime.h>
#include <math.h>

// ---------------------------------------------------------------------------
// Swin block: B=64 H=W=56 C=256 WIN=7 SHIFT=3 HEADS=8 HD=32.
// Input/output dtype (fp32 vs bf16) detected at runtime; bf16 MFMA pipeline.
// Round 6: MLP v4 — wave-private tokens end-to-end. GEMM2 swapped so H stays
// in registers (8-shfl redistribution, no Hs, no 2nd barrier); w2 fragments
// read direct from global (coalesced 1KB b128, L1-hot); LDS 32KB (w1 dbuf
// only), 1 barrier/chunk, 3 blocks/CU target. attn/GEMMs unchanged.
// ---------------------------------------------------------------------------

typedef __attribute__((ext_vector_type(8))) short bf16x8;   // 8 bf16 = 4 VGPRs
typedef __attribute__((ext_vector_type(4))) float f32x4;

#define NTOK 200704   // 64*56*56
#define NN   49
#define NPARAM 4680   // fp32 param block element count
#define TBL_ELEMS (4 * 8 * 49 * 64)

__device__ __forceinline__ float bf2f(unsigned short u) {
    union { unsigned int i; float f; } v; v.i = ((unsigned)u) << 16; return v.f;
}
__device__ __forceinline__ unsigned short f2bf(float f) {
    union { float fv; unsigned int i; } v; v.fv = f;
    return (unsigned short)((v.i + 0x7fffu + ((v.i >> 16) & 1u)) >> 16);  // RNE
}

// async global->LDS 16B (wave-uniform dest base + lane*16 pattern required)
__device__ __forceinline__ void gload_lds16(const unsigned short* g, unsigned short* l) {
    __builtin_amdgcn_global_load_lds(
        (const __attribute__((address_space(1))) unsigned int*)g,
        (__attribute__((address_space(3))) unsigned int*)l, 16, 0, 0);
}

// A&S 7.1.26 erf, |eps|<1.5e-7; gelu(v)=0.5v+0.5|v|*erf(|v|/sqrt2)*sgn-fold
__device__ __forceinline__ float gelu_erf(float v) {
    float av = fabsf(v);
    float x = av * 0.70710678118654752f;
    float t = __builtin_amdgcn_rcpf(fmaf(x, 0.3275911f, 1.0f));
    float p = fmaf(1.061405429f, t, -1.453152027f);
    p = fmaf(p, t, 1.421413741f);
    p = fmaf(p, t, -0.284496736f);
    p = fmaf(p, t, 0.254829592f);
    p = p * t;
    float ex = __builtin_amdgcn_exp2f(x * x * -1.4426950408889634f);
    float E = fmaf(-p, ex, 1.0f);          // erf(|v|/sqrt2)
    return fmaf(0.5f * av, E, 0.5f * v);
}

// ------------------------------ dtype detector -----------------------------
__global__ void detect_kernel(const unsigned short* __restrict__ xu, int* flag) {
    int ln = threadIdx.x;  // 64 threads
    int sane = 0;
    #pragma unroll
    for (int t = 0; t < 16; t++) {
        unsigned u = xu[(ln * 16 + t) * 2];
        unsigned e = (u >> 7) & 0xFF;
        sane += (e >= 0x60 && e <= 0x90) ? 1 : 0;
    }
    #pragma unroll
    for (int off = 32; off; off >>= 1) sane += __shfl_xor(sane, off);
    if (ln == 0) *flag = (sane < 614) ? 1 : 0;
}

__device__ __forceinline__ float ld_any(const void* p, int j, int f) {
    return f ? ((const float*)p)[j] : bf2f(((const unsigned short*)p)[j]);
}

// ------------------------ small params -> fp32 block -----------------------
__global__ void convert_params_kernel(
    const void* ln1_g, const void* ln1_b, const void* qkv_b, const void* proj_b,
    const void* ln2_g, const void* ln2_b, const void* b1, const void* b2,
    const void* rpb, const int* __restrict__ flag, float* __restrict__ dst) {
    int i = blockIdx.x * 256 + threadIdx.x;
    if (i >= NPARAM) return;
    int f = *flag;
    const void* src; int j;
    if      (i < 256)  { src = ln1_g;  j = i; }
    else if (i < 512)  { src = ln1_b;  j = i - 256; }
    else if (i < 1280) { src = qkv_b;  j = i - 512; }
    else if (i < 1536) { src = proj_b; j = i - 1280; }
    else if (i < 1792) { src = ln2_g;  j = i - 1536; }
    else if (i < 2048) { src = ln2_b;  j = i - 1792; }
    else if (i < 3072) { src = b1;     j = i - 2048; }
    else if (i < 3328) { src = b2;     j = i - 3072; }
    else               { src = rpb;    j = i - 3328; }
    dst[i] = ld_any(src, j, f);
}

// -------- combined bias+mask table: tbl[pat][head][q 49][k 64] f32 ---------
__global__ void build_tbl_kernel(const float* __restrict__ rpbF,
                                 float* __restrict__ tbl) {
    int idx = blockIdx.x * 256 + threadIdx.x;
    if (idx >= TBL_ELEMS) return;
    int k = idx & 63;
    int q = (idx >> 6) % 49;
    int h = ((idx >> 6) / 49) & 7;
    int pat = idx / (64 * 49 * 8);
    float v;
    if (k >= 49) {
        v = -1e30f;
    } else {
        int ir = q / 7, ic = q - ir * 7, jr = k / 7, jc = k - jr * 7;
        v = rpbF[((ir - jr + 6) * 13 + (ic - jc + 6)) * 8 + h];
        int rb = pat >> 1, cb = pat & 1;
        int ci = (rb ? (ir < 4 ? 3 : 6) : 0) + (cb ? (ic < 4 ? 1 : 2) : 0);
        int cj = (rb ? (jr < 4 ? 3 : 6) : 0) + (cb ? (jc < 4 ? 1 : 2) : 0);
        if (ci != cj) v -= 100.f;
    }
    tbl[idx] = v;
}

// --------------------- weight transpose (any dtype -> bf16) ----------------
// in: (K,N) row-major -> out: (N,K) row-major bf16
__global__ void transpose_any(const void* __restrict__ in,
                              unsigned short* __restrict__ out, int K, int N,
                              const int* __restrict__ flag) {
    int f = *flag;
    int idx = blockIdx.x * 256 + threadIdx.x;
    if (idx < K * N) {
        int k = idx / N, n = idx - k * N;
        out[n * K + k] = f2bf(ld_any(in, idx, f));
    }
}

// ---- w1 (256,1024) -> 32 chunks of [32 h-rows x 256 k], XOR-pre-swizzled ---
__global__ void relayout_w1(const void* __restrict__ in,
                            unsigned short* __restrict__ out,
                            const int* __restrict__ flag) {
    int f = *flag;
    int idx = blockIdx.x * 256 + threadIdx.x;  // over 256*1024, in elem (k,h)
    if (idx < 256 * 1024) {
        int k = idx >> 10, h = idx & 1023;
        int c = h >> 5, r = h & 31;
        int ks = k ^ ((r & 7) << 3);           // pre-swizzle within 256-short row
        out[c * 8192 + r * 256 + ks] = f2bf(ld_any(in, idx, f));
    }
}

// ------------- w2 (1024,256) -> k-chunk-major blocks (32 x [256n x 32k]) ---
__global__ void relayout_w2(const void* __restrict__ in,
                            unsigned short* __restrict__ out,
                            const int* __restrict__ flag) {
    int f = *flag;
    int idx = blockIdx.x * 256 + threadIdx.x;  // over 1024*256
    if (idx < 1024 * 256) {
        int k = idx >> 8, n = idx & 255;
        int c = k >> 5, kk = k & 31;
        out[c * 8192 + n * 32 + kk] = f2bf(ld_any(in, idx, f));
    }
}

// ------------------------- LN1 + shift + window partition ------------------
__global__ __launch_bounds__(256) void ln1_window_kernel(
    const void* __restrict__ x, const float* __restrict__ paramsF,
    unsigned short* __restrict__ y, const int* __restrict__ flag) {
    int f = *flag;
    int wv = threadIdx.x >> 6, ln = threadIdx.x & 63;
    int tok = blockIdx.x * 4 + wv;
    float v0, v1, v2, v3;
    if (f) {
        float4 pv = *(const float4*)((const float*)x + (size_t)tok * 256 + ln * 4);
        v0 = pv.x; v1 = pv.y; v2 = pv.z; v3 = pv.w;
    } else {
        ushort4 pv = *(const ushort4*)((const unsigned short*)x + (size_t)tok * 256 + ln * 4);
        v0 = bf2f(pv.x); v1 = bf2f(pv.y); v2 = bf2f(pv.z); v3 = bf2f(pv.w);
    }
    float s = v0 + v1 + v2 + v3;
    float sq = v0 * v0 + v1 * v1 + v2 * v2 + v3 * v3;
    #pragma unroll
    for (int off = 32; off; off >>= 1) { s += __shfl_xor(s, off); sq += __shfl_xor(sq, off); }
    float mu = s * (1.f / 256.f);
    float rs = rsqrtf(fmaxf(sq * (1.f / 256.f) - mu * mu, 0.f) + 1e-5f);
    float4 gv = *(const float4*)(paramsF + ln * 4);        // ln1_g
    float4 bv = *(const float4*)(paramsF + 256 + ln * 4);  // ln1_b
    int bb = tok / 3136, hw = tok - bb * 3136;
    int h = hw / 56, w = hw - h * 56;
    int hp = h - 3; hp += (hp < 0) ? 56 : 0;
    int wp = w - 3; wp += (wp < 0) ? 56 : 0;
    int win = (hp / 7) * 8 + (wp / 7);
    int n = (hp % 7) * 7 + (wp % 7);
    size_t drow = ((size_t)bb * 64 + win) * NN + n;
    ushort4 o;
    o.x = f2bf((v0 - mu) * rs * gv.x + bv.x);
    o.y = f2bf((v1 - mu) * rs * gv.y + bv.y);
    o.z = f2bf((v2 - mu) * rs * gv.z + bv.z);
    o.w = f2bf((v3 - mu) * rs * gv.w + bv.w);
    *(ushort4*)(y + drow * 256 + ln * 4) = o;
}

// ------------------------------ GEMM core (K=256) --------------------------
__device__ __forceinline__ void gemm_core_k256(
    const unsigned short* __restrict__ A, const unsigned short* __restrict__ Bt,
    int rowBase, int colBase, unsigned short* As, unsigned short* Bs, f32x4 acc[2][4]) {
    const int tid = threadIdx.x;
    const int wv = tid >> 6, ln = tid & 63;
    const int m16 = ln & 15, q4 = ln >> 4;
    const int ar = tid >> 1, ah = (tid & 1) * 32;
    const int br = tid >> 2, bp = (tid & 3) * 16;
    for (int kb = 0; kb < 256; kb += 64) {
        const unsigned short* ag = A + (size_t)(rowBase + ar) * 256 + kb + ah;
        unsigned short* asd = As + ar * 72 + ah;
        #pragma unroll
        for (int i = 0; i < 4; i++)
            *(bf16x8*)(asd + i * 8) = *(const bf16x8*)(ag + i * 8);
        const unsigned short* bg = Bt + (size_t)(colBase + br) * 256 + kb + bp;
        unsigned short* bsd = Bs + br * 72 + bp;
        #pragma unroll
        for (int i = 0; i < 2; i++)
            *(bf16x8*)(bsd + i * 8) = *(const bf16x8*)(bg + i * 8);
        __syncthreads();
        #pragma unroll
        for (int ks = 0; ks < 64; ks += 32) {
            bf16x8 af[2], bfr[4];
            #pragma unroll
            for (int rt = 0; rt < 2; rt++)
                af[rt] = *(const bf16x8*)(As + (wv * 32 + rt * 16 + m16) * 72 + ks + q4 * 8);
            #pragma unroll
            for (int ct = 0; ct < 4; ct++)
                bfr[ct] = *(const bf16x8*)(Bs + (ct * 16 + m16) * 72 + ks + q4 * 8);
            #pragma unroll
            for (int rt = 0; rt < 2; rt++)
                #pragma unroll
                for (int ct = 0; ct < 4; ct++)
                    acc[rt][ct] = __builtin_amdgcn_mfma_f32_16x16x32_bf16(
                        af[rt], bfr[ct], acc[rt][ct], 0, 0, 0);
        }
        __syncthreads();
    }
}

// ------------------------------- GEMM: QKV ---------------------------------
__global__ __launch_bounds__(256) void gemm_qkv_kernel(
    const unsigned short* __restrict__ A, const unsigned short* __restrict__ Bt,
    const float* __restrict__ bias,  // qkv_b fp32 (768)
    unsigned short* __restrict__ out) {
    __shared__ unsigned short As[128 * 72];
    __shared__ unsigned short Bs[64 * 72];
    const int ln = threadIdx.x & 63, wv = threadIdx.x >> 6;
    const int m16 = ln & 15, q4 = ln >> 4;
    const int rowBase = blockIdx.y * 128, colBase = blockIdx.x * 64;
    f32x4 acc[2][4];
    #pragma unroll
    for (int i = 0; i < 2; i++)
        #pragma unroll
        for (int j = 0; j < 4; j++)
            #pragma unroll
            for (int r = 0; r < 4; r++) acc[i][j][r] = 0.f;
    gemm_core_k256(A, Bt, rowBase, colBase, As, Bs, acc);
    #pragma unroll
    for (int rt = 0; rt < 2; rt++)
        #pragma unroll
        for (int ct = 0; ct < 4; ct++) {
            int col = colBase + ct * 16 + m16;
            float bs = bias[col];
            float scale = (col < 256) ? 0.17677669529663689f : 1.0f;  // q * HD^-0.5
            #pragma unroll
            for (int r = 0; r < 4; r++) {
                int row = rowBase + wv * 32 + rt * 16 + q4 * 4 + r;
                out[(size_t)row * 768 + col] = f2bf((acc[rt][ct][r] + bs) * scale);
            }
        }
}

// ------------------------- GEMM: proj + scatter + residual -----------------
__global__ __launch_bounds__(256) void gemm_proj_kernel(
    const unsigned short* __restrict__ A, const unsigned short* __restrict__ Bt,
    const float* __restrict__ bias,  // proj_b fp32
    const void* __restrict__ xin,    // x natural order (flag dtype)
    unsigned short* __restrict__ x2, const int* __restrict__ flag) {
    __shared__ unsigned short As[128 * 72];
    __shared__ unsigned short Bs[64 * 72];
    const int f = *flag;
    const int ln = threadIdx.x & 63, wv = threadIdx.x >> 6;
    const int m16 = ln & 15, q4 = ln >> 4;
    const int rowBase = blockIdx.y * 128, colBase = blockIdx.x * 64;
    f32x4 acc[2][4];
    #pragma unroll
    for (int i = 0; i < 2; i++)
        #pragma unroll
        for (int j = 0; j < 4; j++)
            #pragma unroll
            for (int r = 0; r < 4; r++) acc[i][j][r] = 0.f;
    gemm_core_k256(A, Bt, rowBase, colBase, As, Bs, acc);
    #pragma unroll
    for (int rt = 0; rt < 2; rt++)
        #pragma unroll
        for (int r = 0; r < 4; r++) {
            int row = rowBase + wv * 32 + rt * 16 + q4 * 4 + r;  // window-order token
            int win = row / NN, n = row - win * NN;
            int bb = win >> 6, wl = win & 63;
            int i7 = n / 7, j7 = n - i7 * 7;
            int hp = (wl >> 3) * 7 + i7 + 3; if (hp >= 56) hp -= 56;  // un-shift
            int wp = (wl & 7) * 7 + j7 + 3;  if (wp >= 56) wp -= 56;
            size_t drow = ((size_t)bb * 3136 + hp * 56 + wp) * 256;
            #pragma unroll
            for (int ct = 0; ct < 4; ct++) {
                int col = colBase + ct * 16 + m16;
                float v = acc[rt][ct][r] + bias[col] + ld_any(xin, drow + col, f);
                x2[drow + col] = f2bf(v);
            }
        }
}

// --------------------------- attention (MFMA) ------------------------------
__global__ __launch_bounds__(256) void attn_mfma_kernel(
    const unsigned short* __restrict__ qkv,  // (NTOK,768): [q|k|v] x head x d
    const float* __restrict__ tbl,           // [4][8][49][64] f32
    unsigned short* __restrict__ o) {        // (NTOK,256) window order
    __shared__ __align__(16) unsigned short Vt[256 * 72];   // [d 256][tok 72]
    __shared__ __align__(16) unsigned short Ps[4][64 * 72]; // per-wave [q 64][k 72]
    const int tid = threadIdx.x;
    const int wv = tid >> 6, ln = tid & 63;
    const int m16 = ln & 15, q4 = ln >> 4;
    const int win = blockIdx.x;
    const size_t wbase = (size_t)win * 49 * 768;

    // ---- build Vt: all heads, tok-contiguous writes (conflict-free) ----
    #pragma unroll
    for (int i = 0; i < 8; i++) {
        int idx = i * 256 + tid;             // ch = idx>>6 (0..31), tok = idx&63
        int ch = idx >> 6, tok = idx & 63;
        if (tok < 49) {
            bf16x8 v = *(const bf16x8*)(qkv + wbase + (size_t)tok * 768 + 512 + ch * 8);
            #pragma unroll
            for (int u = 0; u < 8; u++)
                Vt[(ch * 8 + u) * 72 + tok] = (unsigned short)v[u];
        }
    }
    // zero pad columns 49..71 of row tid (P=0 there anyway; avoid 0*NaN)
    #pragma unroll
    for (int u = 0; u < 23; u++) Vt[tid * 72 + 49 + u] = 0;

    const int wl = win & 63;
    const int pat = (((wl >> 3) == 7) ? 2 : 0) + (((wl & 7) == 7) ? 1 : 0);
    __syncthreads();

    unsigned short* Pw = &Ps[wv][0];
    for (int hh = 0; hh < 2; hh++) {
        const int h = wv * 2 + hh;
        // ---- QK^T swapped: acc[kt][qt] = S^T tile (key row, query col) ----
        bf16x8 kf[4], qf[4];
        #pragma unroll
        for (int t = 0; t < 4; t++) {
            size_t rrow = wbase + (size_t)(t * 16 + m16) * 768 + h * 32 + q4 * 8;
            qf[t] = *(const bf16x8*)(qkv + rrow);
            kf[t] = *(const bf16x8*)(qkv + rrow + 256);
        }
        f32x4 acc[4][4];
        #pragma unroll
        for (int kt = 0; kt < 4; kt++)
            #pragma unroll
            for (int qt = 0; qt < 4; qt++) {
                #pragma unroll
                for (int r = 0; r < 4; r++) acc[kt][qt][r] = 0.f;
                acc[kt][qt] = __builtin_amdgcn_mfma_f32_16x16x32_bf16(
                    kf[kt], qf[qt], acc[kt][qt], 0, 0, 0);
            }

        // ---- softmax per query column (qt, m16); keys lane-local ----
        const float* tb = tbl + ((size_t)(pat * 8 + h) * 49) * 64;
        #pragma unroll
        for (int qt = 0; qt < 4; qt++) {
            int q = qt * 16 + m16;
            int qc = q < 49 ? q : 48;
            float s[4][4];
            float mx = -3e38f;
            #pragma unroll
            for (int kt = 0; kt < 4; kt++) {
                float4 tv = *(const float4*)(tb + qc * 64 + kt * 16 + q4 * 4);
                s[kt][0] = acc[kt][qt][0] + tv.x;
                s[kt][1] = acc[kt][qt][1] + tv.y;
                s[kt][2] = acc[kt][qt][2] + tv.z;
                s[kt][3] = acc[kt][qt][3] + tv.w;
                #pragma unroll
                for (int r = 0; r < 4; r++) mx = fmaxf(mx, s[kt][r]);
            }
            mx = fmaxf(mx, __shfl_xor(mx, 16));
            mx = fmaxf(mx, __shfl_xor(mx, 32));
            float sum = 0.f;
            #pragma unroll
            for (int kt = 0; kt < 4; kt++)
                #pragma unroll
                for (int r = 0; r < 4; r++) {
                    float e = __expf(s[kt][r] - mx);
                    s[kt][r] = e; sum += e;
                }
            sum += __shfl_xor(sum, 16);
            sum += __shfl_xor(sum, 32);
            float inv = 1.f / sum;
            #pragma unroll
            for (int kt = 0; kt < 4; kt++) {
                ushort4 p4;
                p4.x = f2bf(s[kt][0] * inv);
                p4.y = f2bf(s[kt][1] * inv);
                p4.z = f2bf(s[kt][2] * inv);
                p4.w = f2bf(s[kt][3] * inv);
                *(ushort4*)(Pw + q * 72 + kt * 16 + q4 * 4) = p4;
            }
        }

        // ---- PV: O[q][d] = P·V, A=Ps rows, B=Vt rows ----
        f32x4 po[4][2];
        #pragma unroll
        for (int mt = 0; mt < 4; mt++)
            #pragma unroll
            for (int nt = 0; nt < 2; nt++)
                #pragma unroll
                for (int r = 0; r < 4; r++) po[mt][nt][r] = 0.f;
        #pragma unroll
        for (int kstep = 0; kstep < 2; kstep++) {
            bf16x8 pa[4], vb[2];
            #pragma unroll
            for (int mt = 0; mt < 4; mt++)
                pa[mt] = *(const bf16x8*)(Pw + (mt * 16 + m16) * 72 + kstep * 32 + q4 * 8);
            #pragma unroll
            for (int nt = 0; nt < 2; nt++)
                vb[nt] = *(const bf16x8*)(Vt + (h * 32 + nt * 16 + m16) * 72 + kstep * 32 + q4 * 8);
            #pragma unroll
            for (int mt = 0; mt < 4; mt++)
                #pragma unroll
                for (int nt = 0; nt < 2; nt++)
                    po[mt][nt] = __builtin_amdgcn_mfma_f32_16x16x32_bf16(
                        pa[mt], vb[nt], po[mt][nt], 0, 0, 0);
        }

        // ---- store O (rows q<49); 16 lanes write 32B contiguous ----
        #pragma unroll
        for (int mt = 0; mt < 4; mt++)
            #pragma unroll
            for (int r = 0; r < 4; r++) {
                int q = mt * 16 + q4 * 4 + r;
                if (q < 49) {
                    size_t orow = ((size_t)win * 49 + q) * 256 + h * 32;
                    o[orow + m16]      = f2bf(po[mt][0][r]);
                    o[orow + 16 + m16] = f2bf(po[mt][1][r]);
                }
            }
    }
}

// ---------------- fused LN2 + MLP + residual, v4 (wave-private) ------------
// 64 tokens/block, 4 waves; wave owns 16 tokens end-to-end. Per 32-hidden
// chunk: GEMM1 swapped (C: hidden rows x token cols) -> gelu in regs ->
// 8-shfl redistribution to B-frag (k=hidden) -> GEMM2 swapped
// (A = w2 frags DIRECT FROM GLOBAL, coalesced 1KB b128) -> acc2[16] (out^T).
// LDS: w1 double-buffer only (32KB). One barrier per chunk.
__global__ __launch_bounds__(256, 3) void mlp_fused_v4(
    const unsigned short* __restrict__ x2,
    const float* __restrict__ g2F, const float* __restrict__ b2lnF,
    const unsigned short* __restrict__ w1s,  // 32 chunks [32r x 256k] swizzled
    const float* __restrict__ b1F,
    const unsigned short* __restrict__ w2s,  // 32 chunks of [256 col x 32 kk]
    const float* __restrict__ b2F,
    void* __restrict__ out, const int* __restrict__ flag) {
    __shared__ __align__(16) unsigned short Bs1[2][32 * 256];  // 2 x 16KB
    const int f = *flag;
    const int tid = threadIdx.x;
    const int wv = tid >> 6, ln = tid & 63;
    const int m16 = ln & 15, q4 = ln >> 4;
    const int tok0 = blockIdx.x * 64;
    const int tok = tok0 + wv * 16 + m16;    // this lane's token (fixed)

    // ---- issue chunk-0 w1 staging first (overlaps LN2 below) ----
    {
        const unsigned short* s1 = w1s + tid * 8;
        #pragma unroll
        for (int j = 0; j < 4; j++)
            gload_lds16(s1 + j * 2048, &Bs1[0][tid * 8 + j * 2048]);
    }

    // ---- load x2 row + LN2 -> areg (GEMM1 B-fragments, 8 k-steps) ----
    bf16x8 areg[8];
    {
        const unsigned short* xr = x2 + (size_t)tok * 256 + q4 * 8;
        #pragma unroll
        for (int ks = 0; ks < 8; ks++) areg[ks] = *(const bf16x8*)(xr + ks * 32);
        float s = 0.f, sq = 0.f;
        #pragma unroll
        for (int ks = 0; ks < 8; ks++)
            #pragma unroll
            for (int u = 0; u < 8; u++) {
                float v = bf2f((unsigned short)areg[ks][u]);
                s += v; sq += v * v;
            }
        s += __shfl_xor(s, 16); s += __shfl_xor(s, 32);
        sq += __shfl_xor(sq, 16); sq += __shfl_xor(sq, 32);
        float mu = s * (1.f / 256.f);
        float rs = rsqrtf(fmaxf(sq * (1.f / 256.f) - mu * mu, 0.f) + 1e-5f);
        #pragma unroll
        for (int ks = 0; ks < 8; ks++)
            #pragma unroll
            for (int u = 0; u < 8; u++) {
                int kidx = ks * 32 + q4 * 8 + u;
                float v = (bf2f((unsigned short)areg[ks][u]) - mu) * rs * g2F[kidx] + b2lnF[kidx];
                areg[ks][u] = (short)f2bf(v);
            }
    }

    f32x4 acc2[16];   // out^T: acc2[ct2] -> cols ct2*16 + q4*4 + r, token = m16
    #pragma unroll
    for (int i = 0; i < 16; i++)
        #pragma unroll
        for (int r = 0; r < 4; r++) acc2[i][r] = 0.f;

    const int l1 = m16 + (((2 * q4) & 3) << 4);      // shfl src lanes
    const int l2 = m16 + (((2 * q4 + 1) & 3) << 4);
    const bool hi = q4 >= 2;

    #pragma unroll 1
    for (int c = 0; c < 32; ++c) {
        const int cur = c & 1;
        asm volatile("s_waitcnt vmcnt(0)" ::: "memory");
        __builtin_amdgcn_s_barrier();
        __builtin_amdgcn_sched_barrier(0);

        // ---- issue w1 staging for chunk c+1 ----
        if (c + 1 < 32) {
            const unsigned short* s1 = w1s + (size_t)(c + 1) * 8192 + tid * 8;
            unsigned short* d1 = &Bs1[cur ^ 1][tid * 8];
            #pragma unroll
            for (int j = 0; j < 4; j++)
                gload_lds16(s1 + j * 2048, d1 + j * 2048);
        }
        __builtin_amdgcn_sched_barrier(0);

        // ---- GEMM1 swapped: acc1[ct] = H^T[hidden ct*16+q4*4+r][token m16] ----
        f32x4 acc1[2];
        #pragma unroll
        for (int ct = 0; ct < 2; ct++)
            #pragma unroll
            for (int r = 0; r < 4; r++) acc1[ct][r] = 0.f;
        const unsigned short* b1base = &Bs1[cur][0];
        #pragma unroll
        for (int ks = 0; ks < 8; ks++) {
            int kidx = (ks * 32 + q4 * 8) ^ ((m16 & 7) << 3);  // un-swizzle
            #pragma unroll
            for (int ct = 0; ct < 2; ct++) {
                bf16x8 wfr = *(const bf16x8*)(b1base + (ct * 16 + m16) * 256 + kidx);
                acc1[ct] = __builtin_amdgcn_mfma_f32_16x16x32_bf16(wfr, areg[ks], acc1[ct], 0, 0, 0);
            }
        }

        // ---- bias + gelu -> packed bf16 (2 dwords per ct) ----
        union { ushort4 s; unsigned int u[2]; } pk[2];
        #pragma unroll
        for (int ct = 0; ct < 2; ct++) {
            float4 bb = *(const float4*)(b1F + c * 32 + ct * 16 + q4 * 4);
            pk[ct].s.x = f2bf(gelu_erf(acc1[ct][0] + bb.x));
            pk[ct].s.y = f2bf(gelu_erf(acc1[ct][1] + bb.y));
            pk[ct].s.z = f2bf(gelu_erf(acc1[ct][2] + bb.z));
            pk[ct].s.w = f2bf(gelu_erf(acc1[ct][3] + bb.w));
        }

        // ---- redistribute to GEMM2 B-frag: lane needs H[token m16][q4*8+u] ----
        unsigned int r0x = __shfl(pk[0].u[0], l1), r0y = __shfl(pk[0].u[1], l1);
        unsigned int r0z = __shfl(pk[0].u[0], l2), r0w = __shfl(pk[0].u[1], l2);
        unsigned int r1x = __shfl(pk[1].u[0], l1), r1y = __shfl(pk[1].u[1], l1);
        unsigned int r1z = __shfl(pk[1].u[0], l2), r1w = __shfl(pk[1].u[1], l2);
        union { bf16x8 v; unsigned int u[4]; } bfrag;
        bfrag.u[0] = hi ? r1x : r0x;
        bfrag.u[1] = hi ? r1y : r0y;
        bfrag.u[2] = hi ? r1z : r0z;
        bfrag.u[3] = hi ? r1w : r0w;

        // ---- GEMM2 swapped: A = w2 frags from global (coalesced 1KB/tile) ----
        const unsigned short* w2g = w2s + (size_t)c * 8192 + m16 * 32 + q4 * 8;
        #pragma unroll
        for (int g = 0; g < 4; g++) {
            bf16x8 wf[4];
            #pragma unroll
            for (int j = 0; j < 4; j++)
                wf[j] = *(const bf16x8*)(w2g + (g * 4 + j) * 512);
            #pragma unroll
            for (int j = 0; j < 4; j++)
                acc2[g * 4 + j] = __builtin_amdgcn_mfma_f32_16x16x32_bf16(
                    wf[j], bfrag.v, acc2[g * 4 + j], 0, 0, 0);
        }
    }

    // ---- epilogue: + b2 + residual (b64 read), vectorized store ----
    const size_t trow = (size_t)tok * 256;
    #pragma unroll
    for (int ct2 = 0; ct2 < 16; ct2++) {
        int col0 = ct2 * 16 + q4 * 4;
        float4 bb = *(const float4*)(b2F + col0);
        ushort4 rv = *(const ushort4*)(x2 + trow + col0);
        float v0 = acc2[ct2][0] + bb.x + bf2f(rv.x);
        float v1 = acc2[ct2][1] + bb.y + bf2f(rv.y);
        float v2 = acc2[ct2][2] + bb.z + bf2f(rv.z);
        float v3 = acc2[ct2][3] + bb.w + bf2f(rv.w);
        if (f) {
            float4 ov = {v0, v1, v2, v3};
            *(float4*)((float*)out + trow + col0) = ov;
        } else {
            ushort4 ov;
            ov.x = f2bf(v0); ov.y = f2bf(v1); ov.z = f2bf(v2); ov.w = f2bf(v3);
            *(ushort4*)((unsigned short*)out + trow + col0) = ov;
        }
    }
}

// ------------------------------- launcher ----------------------------------
extern "C" void kernel_launch(void* const* d_in, const int* in_sizes, int n_in,
                              void* d_out, int out_size, void* d_ws, size_t ws_size,
                              hipStream_t stream) {
    const void* x      = d_in[0];
    const void* qkv_w  = d_in[3];
    const void* proj_w = d_in[6];
    const void* w1     = d_in[10];
    const void* w2     = d_in[12];

    char* ws = (char*)d_ws;
    size_t off = 0;
    unsigned short* y = (unsigned short*)(ws + off);       // LN1 out; reused as attn out
    off += (size_t)NTOK * 256 * 2;
    size_t qkv_off = off;
    unsigned short* qkv = (unsigned short*)(ws + off);     // (NTOK,768) bf16
    off += (size_t)NTOK * 768 * 2;
    unsigned short* x2 = (unsigned short*)(ws + qkv_off);  // overlaps qkv (dead by then)
    unsigned short* o = y;                                 // overlaps y (dead after QKV GEMM)
    unsigned short* qkvWt = (unsigned short*)(ws + off); off += 768 * 256 * 2;
    unsigned short* projWt = (unsigned short*)(ws + off); off += 256 * 256 * 2;
    unsigned short* w1s = (unsigned short*)(ws + off); off += 1024 * 256 * 2;
    unsigned short* w2s = (unsigned short*)(ws + off); off += 256 * 1024 * 2;
    float* paramsF = (float*)(ws + off); off += NPARAM * 4;
    int* flag = (int*)(ws + off); off += 16;
    float* tbl = (float*)(ws + off); off += (size_t)TBL_ELEMS * 4;
    (void)ws_size; (void)in_sizes; (void)n_in; (void)out_size;

    detect_kernel<<<1, 64, 0, stream>>>((const unsigned short*)x, flag);
    convert_params_kernel<<<(NPARAM + 255) / 256, 256, 0, stream>>>(
        d_in[1], d_in[2], d_in[4], d_in[7], d_in[8], d_in[9], d_in[11], d_in[13],
        d_in[5], flag, paramsF);
    build_tbl_kernel<<<(TBL_ELEMS + 255) / 256, 256, 0, stream>>>(paramsF + 3328, tbl);
    transpose_any<<<(256 * 768 + 255) / 256, 256, 0, stream>>>(qkv_w, qkvWt, 256, 768, flag);
    transpose_any<<<(256 * 256 + 255) / 256, 256, 0, stream>>>(proj_w, projWt, 256, 256, flag);
    relayout_w1<<<(256 * 1024 + 255) / 256, 256, 0, stream>>>(w1, w1s, flag);
    relayout_w2<<<(1024 * 256 + 255) / 256, 256, 0, stream>>>(w2, w2s, flag);

    ln1_window_kernel<<<NTOK / 4, 256, 0, stream>>>(x, paramsF, y, flag);
    gemm_qkv_kernel<<<dim3(768 / 64, NTOK / 128), 256, 0, stream>>>(y, qkvWt, paramsF + 512, qkv);
    attn_mfma_kernel<<<4096, 256, 0, stream>>>(qkv, tbl, o);
    gemm_proj_kernel<<<dim3(256 / 64, NTOK / 128), 256, 0, stream>>>(
        o, projWt, paramsF + 1280, x, x2, flag);
    mlp_fused_v4<<<NTOK / 64, 256, 0, stream>>>(
        x2, paramsF + 1536, paramsF + 1792, w1s, paramsF + 2048, w2s, paramsF + 3072, d_out, flag);
}

// Round 4
// 1478.051 us; speedup vs baseline: 1.0141x; 1.0141x over previous
//
#include <hip/hip_runtime.h>
#include <math.h>

// ---------------------------------------------------------------------------
// Swin block: B=64 H=W=56 C=256 WIN=7 SHIFT=3 HEADS=8 HD=32.
// Input/output dtype (fp32 vs bf16) detected at runtime; bf16 MFMA pipeline.
// Round 7: MLP v5 — 128 tokens/block (512 thr, 8 waves) halves weight L2
// traffic; w1 AND w2 double-buffered via global_load_lds (64KB LDS, both
// XOR-pre-swizzled, T21); wave-private H via 8-shfl redistribution (no Hs,
// one barrier/chunk); setprio around MFMA clusters. attn/GEMMs unchanged.
// ---------------------------------------------------------------------------

typedef __attribute__((ext_vector_type(8))) short bf16x8;   // 8 bf16 = 4 VGPRs
typedef __attribute__((ext_vector_type(4))) float f32x4;

#define NTOK 200704   // 64*56*56
#define NN   49
#define NPARAM 4680   // fp32 param block element count
#define TBL_ELEMS (4 * 8 * 49 * 64)

__device__ __forceinline__ float bf2f(unsigned short u) {
    union { unsigned int i; float f; } v; v.i = ((unsigned)u) << 16; return v.f;
}
__device__ __forceinline__ unsigned short f2bf(float f) {
    union { float fv; unsigned int i; } v; v.fv = f;
    return (unsigned short)((v.i + 0x7fffu + ((v.i >> 16) & 1u)) >> 16);  // RNE
}

// async global->LDS 16B (wave-uniform dest base + lane*16 pattern required)
__device__ __forceinline__ void gload_lds16(const unsigned short* g, unsigned short* l) {
    __builtin_amdgcn_global_load_lds(
        (const __attribute__((address_space(1))) unsigned int*)g,
        (__attribute__((address_space(3))) unsigned int*)l, 16, 0, 0);
}

// A&S 7.1.26 erf, |eps|<1.5e-7; gelu(v)=0.5v+0.5|v|*erf(|v|/sqrt2)*sgn-fold
__device__ __forceinline__ float gelu_erf(float v) {
    float av = fabsf(v);
    float x = av * 0.70710678118654752f;
    float t = __builtin_amdgcn_rcpf(fmaf(x, 0.3275911f, 1.0f));
    float p = fmaf(1.061405429f, t, -1.453152027f);
    p = fmaf(p, t, 1.421413741f);
    p = fmaf(p, t, -0.284496736f);
    p = fmaf(p, t, 0.254829592f);
    p = p * t;
    float ex = __builtin_amdgcn_exp2f(x * x * -1.4426950408889634f);
    float E = fmaf(-p, ex, 1.0f);          // erf(|v|/sqrt2)
    return fmaf(0.5f * av, E, 0.5f * v);
}

// ------------------------------ dtype detector -----------------------------
__global__ void detect_kernel(const unsigned short* __restrict__ xu, int* flag) {
    int ln = threadIdx.x;  // 64 threads
    int sane = 0;
    #pragma unroll
    for (int t = 0; t < 16; t++) {
        unsigned u = xu[(ln * 16 + t) * 2];
        unsigned e = (u >> 7) & 0xFF;
        sane += (e >= 0x60 && e <= 0x90) ? 1 : 0;
    }
    #pragma unroll
    for (int off = 32; off; off >>= 1) sane += __shfl_xor(sane, off);
    if (ln == 0) *flag = (sane < 614) ? 1 : 0;
}

__device__ __forceinline__ float ld_any(const void* p, int j, int f) {
    return f ? ((const float*)p)[j] : bf2f(((const unsigned short*)p)[j]);
}

// ------------------------ small params -> fp32 block -----------------------
__global__ void convert_params_kernel(
    const void* ln1_g, const void* ln1_b, const void* qkv_b, const void* proj_b,
    const void* ln2_g, const void* ln2_b, const void* b1, const void* b2,
    const void* rpb, const int* __restrict__ flag, float* __restrict__ dst) {
    int i = blockIdx.x * 256 + threadIdx.x;
    if (i >= NPARAM) return;
    int f = *flag;
    const void* src; int j;
    if      (i < 256)  { src = ln1_g;  j = i; }
    else if (i < 512)  { src = ln1_b;  j = i - 256; }
    else if (i < 1280) { src = qkv_b;  j = i - 512; }
    else if (i < 1536) { src = proj_b; j = i - 1280; }
    else if (i < 1792) { src = ln2_g;  j = i - 1536; }
    else if (i < 2048) { src = ln2_b;  j = i - 1792; }
    else if (i < 3072) { src = b1;     j = i - 2048; }
    else if (i < 3328) { src = b2;     j = i - 3072; }
    else               { src = rpb;    j = i - 3328; }
    dst[i] = ld_any(src, j, f);
}

// -------- combined bias+mask table: tbl[pat][head][q 49][k 64] f32 ---------
__global__ void build_tbl_kernel(const float* __restrict__ rpbF,
                                 float* __restrict__ tbl) {
    int idx = blockIdx.x * 256 + threadIdx.x;
    if (idx >= TBL_ELEMS) return;
    int k = idx & 63;
    int q = (idx >> 6) % 49;
    int h = ((idx >> 6) / 49) & 7;
    int pat = idx / (64 * 49 * 8);
    float v;
    if (k >= 49) {
        v = -1e30f;
    } else {
        int ir = q / 7, ic = q - ir * 7, jr = k / 7, jc = k - jr * 7;
        v = rpbF[((ir - jr + 6) * 13 + (ic - jc + 6)) * 8 + h];
        int rb = pat >> 1, cb = pat & 1;
        int ci = (rb ? (ir < 4 ? 3 : 6) : 0) + (cb ? (ic < 4 ? 1 : 2) : 0);
        int cj = (rb ? (jr < 4 ? 3 : 6) : 0) + (cb ? (jc < 4 ? 1 : 2) : 0);
        if (ci != cj) v -= 100.f;
    }
    tbl[idx] = v;
}

// --------------------- weight transpose (any dtype -> bf16) ----------------
// in: (K,N) row-major -> out: (N,K) row-major bf16
__global__ void transpose_any(const void* __restrict__ in,
                              unsigned short* __restrict__ out, int K, int N,
                              const int* __restrict__ flag) {
    int f = *flag;
    int idx = blockIdx.x * 256 + threadIdx.x;
    if (idx < K * N) {
        int k = idx / N, n = idx - k * N;
        out[n * K + k] = f2bf(ld_any(in, idx, f));
    }
}

// ---- w1 (256,1024) -> 32 chunks of [32 h-rows x 256 k], XOR-pre-swizzled ---
__global__ void relayout_w1(const void* __restrict__ in,
                            unsigned short* __restrict__ out,
                            const int* __restrict__ flag) {
    int f = *flag;
    int idx = blockIdx.x * 256 + threadIdx.x;  // over 256*1024, in elem (k,h)
    if (idx < 256 * 1024) {
        int k = idx >> 10, h = idx & 1023;
        int c = h >> 5, r = h & 31;
        int ks = k ^ ((r & 7) << 3);           // pre-swizzle within 256-short row
        out[c * 8192 + r * 256 + ks] = f2bf(ld_any(in, idx, f));
    }
}

// ------------- w2 (1024,256) -> k-chunk-major blocks (32 x [256n x 32k]) ---
// XOR-pre-swizzled: slot = kk ^ ((n&6)<<2) (16B units) so LDS ds_read_b128
// of A-frags (16 lanes = 16 consecutive n at same kk-base) is 2-way-bank max.
__global__ void relayout_w2(const void* __restrict__ in,
                            unsigned short* __restrict__ out,
                            const int* __restrict__ flag) {
    int f = *flag;
    int idx = blockIdx.x * 256 + threadIdx.x;  // over 1024*256
    if (idx < 1024 * 256) {
        int k = idx >> 8, n = idx & 255;
        int c = k >> 5, kk = k & 31;
        int slot = kk ^ ((n & 6) << 2);
        out[c * 8192 + n * 32 + slot] = f2bf(ld_any(in, idx, f));
    }
}

// ------------------------- LN1 + shift + window partition ------------------
__global__ __launch_bounds__(256) void ln1_window_kernel(
    const void* __restrict__ x, const float* __restrict__ paramsF,
    unsigned short* __restrict__ y, const int* __restrict__ flag) {
    int f = *flag;
    int wv = threadIdx.x >> 6, ln = threadIdx.x & 63;
    int tok = blockIdx.x * 4 + wv;
    float v0, v1, v2, v3;
    if (f) {
        float4 pv = *(const float4*)((const float*)x + (size_t)tok * 256 + ln * 4);
        v0 = pv.x; v1 = pv.y; v2 = pv.z; v3 = pv.w;
    } else {
        ushort4 pv = *(const ushort4*)((const unsigned short*)x + (size_t)tok * 256 + ln * 4);
        v0 = bf2f(pv.x); v1 = bf2f(pv.y); v2 = bf2f(pv.z); v3 = bf2f(pv.w);
    }
    float s = v0 + v1 + v2 + v3;
    float sq = v0 * v0 + v1 * v1 + v2 * v2 + v3 * v3;
    #pragma unroll
    for (int off = 32; off; off >>= 1) { s += __shfl_xor(s, off); sq += __shfl_xor(sq, off); }
    float mu = s * (1.f / 256.f);
    float rs = rsqrtf(fmaxf(sq * (1.f / 256.f) - mu * mu, 0.f) + 1e-5f);
    float4 gv = *(const float4*)(paramsF + ln * 4);        // ln1_g
    float4 bv = *(const float4*)(paramsF + 256 + ln * 4);  // ln1_b
    int bb = tok / 3136, hw = tok - bb * 3136;
    int h = hw / 56, w = hw - h * 56;
    int hp = h - 3; hp += (hp < 0) ? 56 : 0;
    int wp = w - 3; wp += (wp < 0) ? 56 : 0;
    int win = (hp / 7) * 8 + (wp / 7);
    int n = (hp % 7) * 7 + (wp % 7);
    size_t drow = ((size_t)bb * 64 + win) * NN + n;
    ushort4 o;
    o.x = f2bf((v0 - mu) * rs * gv.x + bv.x);
    o.y = f2bf((v1 - mu) * rs * gv.y + bv.y);
    o.z = f2bf((v2 - mu) * rs * gv.z + bv.z);
    o.w = f2bf((v3 - mu) * rs * gv.w + bv.w);
    *(ushort4*)(y + drow * 256 + ln * 4) = o;
}

// ------------------------------ GEMM core (K=256) --------------------------
__device__ __forceinline__ void gemm_core_k256(
    const unsigned short* __restrict__ A, const unsigned short* __restrict__ Bt,
    int rowBase, int colBase, unsigned short* As, unsigned short* Bs, f32x4 acc[2][4]) {
    const int tid = threadIdx.x;
    const int wv = tid >> 6, ln = tid & 63;
    const int m16 = ln & 15, q4 = ln >> 4;
    const int ar = tid >> 1, ah = (tid & 1) * 32;
    const int br = tid >> 2, bp = (tid & 3) * 16;
    for (int kb = 0; kb < 256; kb += 64) {
        const unsigned short* ag = A + (size_t)(rowBase + ar) * 256 + kb + ah;
        unsigned short* asd = As + ar * 72 + ah;
        #pragma unroll
        for (int i = 0; i < 4; i++)
            *(bf16x8*)(asd + i * 8) = *(const bf16x8*)(ag + i * 8);
        const unsigned short* bg = Bt + (size_t)(colBase + br) * 256 + kb + bp;
        unsigned short* bsd = Bs + br * 72 + bp;
        #pragma unroll
        for (int i = 0; i < 2; i++)
            *(bf16x8*)(bsd + i * 8) = *(const bf16x8*)(bg + i * 8);
        __syncthreads();
        #pragma unroll
        for (int ks = 0; ks < 64; ks += 32) {
            bf16x8 af[2], bfr[4];
            #pragma unroll
            for (int rt = 0; rt < 2; rt++)
                af[rt] = *(const bf16x8*)(As + (wv * 32 + rt * 16 + m16) * 72 + ks + q4 * 8);
            #pragma unroll
            for (int ct = 0; ct < 4; ct++)
                bfr[ct] = *(const bf16x8*)(Bs + (ct * 16 + m16) * 72 + ks + q4 * 8);
            #pragma unroll
            for (int rt = 0; rt < 2; rt++)
                #pragma unroll
                for (int ct = 0; ct < 4; ct++)
                    acc[rt][ct] = __builtin_amdgcn_mfma_f32_16x16x32_bf16(
                        af[rt], bfr[ct], acc[rt][ct], 0, 0, 0);
        }
        __syncthreads();
    }
}

// ------------------------------- GEMM: QKV ---------------------------------
__global__ __launch_bounds__(256) void gemm_qkv_kernel(
    const unsigned short* __restrict__ A, const unsigned short* __restrict__ Bt,
    const float* __restrict__ bias,  // qkv_b fp32 (768)
    unsigned short* __restrict__ out) {
    __shared__ unsigned short As[128 * 72];
    __shared__ unsigned short Bs[64 * 72];
    const int ln = threadIdx.x & 63, wv = threadIdx.x >> 6;
    const int m16 = ln & 15, q4 = ln >> 4;
    const int rowBase = blockIdx.y * 128, colBase = blockIdx.x * 64;
    f32x4 acc[2][4];
    #pragma unroll
    for (int i = 0; i < 2; i++)
        #pragma unroll
        for (int j = 0; j < 4; j++)
            #pragma unroll
            for (int r = 0; r < 4; r++) acc[i][j][r] = 0.f;
    gemm_core_k256(A, Bt, rowBase, colBase, As, Bs, acc);
    #pragma unroll
    for (int rt = 0; rt < 2; rt++)
        #pragma unroll
        for (int ct = 0; ct < 4; ct++) {
            int col = colBase + ct * 16 + m16;
            float bs = bias[col];
            float scale = (col < 256) ? 0.17677669529663689f : 1.0f;  // q * HD^-0.5
            #pragma unroll
            for (int r = 0; r < 4; r++) {
                int row = rowBase + wv * 32 + rt * 16 + q4 * 4 + r;
                out[(size_t)row * 768 + col] = f2bf((acc[rt][ct][r] + bs) * scale);
            }
        }
}

// ------------------------- GEMM: proj + scatter + residual -----------------
__global__ __launch_bounds__(256) void gemm_proj_kernel(
    const unsigned short* __restrict__ A, const unsigned short* __restrict__ Bt,
    const float* __restrict__ bias,  // proj_b fp32
    const void* __restrict__ xin,    // x natural order (flag dtype)
    unsigned short* __restrict__ x2, const int* __restrict__ flag) {
    __shared__ unsigned short As[128 * 72];
    __shared__ unsigned short Bs[64 * 72];
    const int f = *flag;
    const int ln = threadIdx.x & 63, wv = threadIdx.x >> 6;
    const int m16 = ln & 15, q4 = ln >> 4;
    const int rowBase = blockIdx.y * 128, colBase = blockIdx.x * 64;
    f32x4 acc[2][4];
    #pragma unroll
    for (int i = 0; i < 2; i++)
        #pragma unroll
        for (int j = 0; j < 4; j++)
            #pragma unroll
            for (int r = 0; r < 4; r++) acc[i][j][r] = 0.f;
    gemm_core_k256(A, Bt, rowBase, colBase, As, Bs, acc);
    #pragma unroll
    for (int rt = 0; rt < 2; rt++)
        #pragma unroll
        for (int r = 0; r < 4; r++) {
            int row = rowBase + wv * 32 + rt * 16 + q4 * 4 + r;  // window-order token
            int win = row / NN, n = row - win * NN;
            int bb = win >> 6, wl = win & 63;
            int i7 = n / 7, j7 = n - i7 * 7;
            int hp = (wl >> 3) * 7 + i7 + 3; if (hp >= 56) hp -= 56;  // un-shift
            int wp = (wl & 7) * 7 + j7 + 3;  if (wp >= 56) wp -= 56;
            size_t drow = ((size_t)bb * 3136 + hp * 56 + wp) * 256;
            #pragma unroll
            for (int ct = 0; ct < 4; ct++) {
                int col = colBase + ct * 16 + m16;
                float v = acc[rt][ct][r] + bias[col] + ld_any(xin, drow + col, f);
                x2[drow + col] = f2bf(v);
            }
        }
}

// --------------------------- attention (MFMA) ------------------------------
__global__ __launch_bounds__(256) void attn_mfma_kernel(
    const unsigned short* __restrict__ qkv,  // (NTOK,768): [q|k|v] x head x d
    const float* __restrict__ tbl,           // [4][8][49][64] f32
    unsigned short* __restrict__ o) {        // (NTOK,256) window order
    __shared__ __align__(16) unsigned short Vt[256 * 72];   // [d 256][tok 72]
    __shared__ __align__(16) unsigned short Ps[4][64 * 72]; // per-wave [q 64][k 72]
    const int tid = threadIdx.x;
    const int wv = tid >> 6, ln = tid & 63;
    const int m16 = ln & 15, q4 = ln >> 4;
    const int win = blockIdx.x;
    const size_t wbase = (size_t)win * 49 * 768;

    // ---- build Vt: all heads, tok-contiguous writes (conflict-free) ----
    #pragma unroll
    for (int i = 0; i < 8; i++) {
        int idx = i * 256 + tid;             // ch = idx>>6 (0..31), tok = idx&63
        int ch = idx >> 6, tok = idx & 63;
        if (tok < 49) {
            bf16x8 v = *(const bf16x8*)(qkv + wbase + (size_t)tok * 768 + 512 + ch * 8);
            #pragma unroll
            for (int u = 0; u < 8; u++)
                Vt[(ch * 8 + u) * 72 + tok] = (unsigned short)v[u];
        }
    }
    // zero pad columns 49..71 of row tid (P=0 there anyway; avoid 0*NaN)
    #pragma unroll
    for (int u = 0; u < 23; u++) Vt[tid * 72 + 49 + u] = 0;

    const int wl = win & 63;
    const int pat = (((wl >> 3) == 7) ? 2 : 0) + (((wl & 7) == 7) ? 1 : 0);
    __syncthreads();

    unsigned short* Pw = &Ps[wv][0];
    for (int hh = 0; hh < 2; hh++) {
        const int h = wv * 2 + hh;
        // ---- QK^T swapped: acc[kt][qt] = S^T tile (key row, query col) ----
        bf16x8 kf[4], qf[4];
        #pragma unroll
        for (int t = 0; t < 4; t++) {
            size_t rrow = wbase + (size_t)(t * 16 + m16) * 768 + h * 32 + q4 * 8;
            qf[t] = *(const bf16x8*)(qkv + rrow);
            kf[t] = *(const bf16x8*)(qkv + rrow + 256);
        }
        f32x4 acc[4][4];
        #pragma unroll
        for (int kt = 0; kt < 4; kt++)
            #pragma unroll
            for (int qt = 0; qt < 4; qt++) {
                #pragma unroll
                for (int r = 0; r < 4; r++) acc[kt][qt][r] = 0.f;
                acc[kt][qt] = __builtin_amdgcn_mfma_f32_16x16x32_bf16(
                    kf[kt], qf[qt], acc[kt][qt], 0, 0, 0);
            }

        // ---- softmax per query column (qt, m16); keys lane-local ----
        const float* tb = tbl + ((size_t)(pat * 8 + h) * 49) * 64;
        #pragma unroll
        for (int qt = 0; qt < 4; qt++) {
            int q = qt * 16 + m16;
            int qc = q < 49 ? q : 48;
            float s[4][4];
            float mx = -3e38f;
            #pragma unroll
            for (int kt = 0; kt < 4; kt++) {
                float4 tv = *(const float4*)(tb + qc * 64 + kt * 16 + q4 * 4);
                s[kt][0] = acc[kt][qt][0] + tv.x;
                s[kt][1] = acc[kt][qt][1] + tv.y;
                s[kt][2] = acc[kt][qt][2] + tv.z;
                s[kt][3] = acc[kt][qt][3] + tv.w;
                #pragma unroll
                for (int r = 0; r < 4; r++) mx = fmaxf(mx, s[kt][r]);
            }
            mx = fmaxf(mx, __shfl_xor(mx, 16));
            mx = fmaxf(mx, __shfl_xor(mx, 32));
            float sum = 0.f;
            #pragma unroll
            for (int kt = 0; kt < 4; kt++)
                #pragma unroll
                for (int r = 0; r < 4; r++) {
                    float e = __expf(s[kt][r] - mx);
                    s[kt][r] = e; sum += e;
                }
            sum += __shfl_xor(sum, 16);
            sum += __shfl_xor(sum, 32);
            float inv = 1.f / sum;
            #pragma unroll
            for (int kt = 0; kt < 4; kt++) {
                ushort4 p4;
                p4.x = f2bf(s[kt][0] * inv);
                p4.y = f2bf(s[kt][1] * inv);
                p4.z = f2bf(s[kt][2] * inv);
                p4.w = f2bf(s[kt][3] * inv);
                *(ushort4*)(Pw + q * 72 + kt * 16 + q4 * 4) = p4;
            }
        }

        // ---- PV: O[q][d] = P·V, A=Ps rows, B=Vt rows ----
        f32x4 po[4][2];
        #pragma unroll
        for (int mt = 0; mt < 4; mt++)
            #pragma unroll
            for (int nt = 0; nt < 2; nt++)
                #pragma unroll
                for (int r = 0; r < 4; r++) po[mt][nt][r] = 0.f;
        #pragma unroll
        for (int kstep = 0; kstep < 2; kstep++) {
            bf16x8 pa[4], vb[2];
            #pragma unroll
            for (int mt = 0; mt < 4; mt++)
                pa[mt] = *(const bf16x8*)(Pw + (mt * 16 + m16) * 72 + kstep * 32 + q4 * 8);
            #pragma unroll
            for (int nt = 0; nt < 2; nt++)
                vb[nt] = *(const bf16x8*)(Vt + (h * 32 + nt * 16 + m16) * 72 + kstep * 32 + q4 * 8);
            #pragma unroll
            for (int mt = 0; mt < 4; mt++)
                #pragma unroll
                for (int nt = 0; nt < 2; nt++)
                    po[mt][nt] = __builtin_amdgcn_mfma_f32_16x16x32_bf16(
                        pa[mt], vb[nt], po[mt][nt], 0, 0, 0);
        }

        // ---- store O (rows q<49); 16 lanes write 32B contiguous ----
        #pragma unroll
        for (int mt = 0; mt < 4; mt++)
            #pragma unroll
            for (int r = 0; r < 4; r++) {
                int q = mt * 16 + q4 * 4 + r;
                if (q < 49) {
                    size_t orow = ((size_t)win * 49 + q) * 256 + h * 32;
                    o[orow + m16]      = f2bf(po[mt][0][r]);
                    o[orow + 16 + m16] = f2bf(po[mt][1][r]);
                }
            }
    }
}

// ---------------- fused LN2 + MLP + residual, v5 (128-tok, dual dbuf) ------
// 128 tokens/block, 8 waves; wave owns 16 tokens end-to-end. Per 32-hidden
// chunk: GEMM1 swapped (w1 from LDS dbuf) -> gelu in regs -> 8-shfl
// redistribution -> GEMM2 swapped (w2 from LDS dbuf, XOR-swizzled) ->
// acc2[16] (out^T). One barrier/chunk; staging one chunk ahead via
// global_load_lds (4 x 16B/thread/chunk); setprio around MFMA clusters.
__global__ __launch_bounds__(512, 2) void mlp_fused_v5(
    const unsigned short* __restrict__ x2,
    const float* __restrict__ g2F, const float* __restrict__ b2lnF,
    const unsigned short* __restrict__ w1s,  // 32 chunks [32r x 256k] swizzled
    const float* __restrict__ b1F,
    const unsigned short* __restrict__ w2s,  // 32 chunks [256n x 32k] swizzled
    const float* __restrict__ b2F,
    void* __restrict__ out, const int* __restrict__ flag) {
    __shared__ __align__(16) unsigned short Bs1[2][32 * 256];  // 2 x 16KB
    __shared__ __align__(16) unsigned short Bs2[2][256 * 32];  // 2 x 16KB
    const int f = *flag;
    const int tid = threadIdx.x;             // 0..511
    const int wv = tid >> 6, ln = tid & 63;
    const int m16 = ln & 15, q4 = ln >> 4;
    const int tok = blockIdx.x * 128 + wv * 16 + m16;  // this lane's token

    // ---- issue chunk-0 staging first (overlaps LN2 below) ----
    {
        const unsigned short* s1 = w1s + tid * 8;
        const unsigned short* s2 = w2s + tid * 8;
        #pragma unroll
        for (int j = 0; j < 2; j++) {
            gload_lds16(s1 + j * 4096, &Bs1[0][tid * 8 + j * 4096]);
            gload_lds16(s2 + j * 4096, &Bs2[0][tid * 8 + j * 4096]);
        }
    }

    // ---- load x2 row + LN2 -> areg (GEMM1 B-fragments, 8 k-steps) ----
    bf16x8 areg[8];
    {
        const unsigned short* xr = x2 + (size_t)tok * 256 + q4 * 8;
        #pragma unroll
        for (int ks = 0; ks < 8; ks++) areg[ks] = *(const bf16x8*)(xr + ks * 32);
        float s = 0.f, sq = 0.f;
        #pragma unroll
        for (int ks = 0; ks < 8; ks++)
            #pragma unroll
            for (int u = 0; u < 8; u++) {
                float v = bf2f((unsigned short)areg[ks][u]);
                s += v; sq += v * v;
            }
        s += __shfl_xor(s, 16); s += __shfl_xor(s, 32);
        sq += __shfl_xor(sq, 16); sq += __shfl_xor(sq, 32);
        float mu = s * (1.f / 256.f);
        float rs = rsqrtf(fmaxf(sq * (1.f / 256.f) - mu * mu, 0.f) + 1e-5f);
        #pragma unroll
        for (int ks = 0; ks < 8; ks++)
            #pragma unroll
            for (int u = 0; u < 8; u++) {
                int kidx = ks * 32 + q4 * 8 + u;
                float v = (bf2f((unsigned short)areg[ks][u]) - mu) * rs * g2F[kidx] + b2lnF[kidx];
                areg[ks][u] = (short)f2bf(v);
            }
    }

    f32x4 acc2[16];   // out^T: acc2[ct2] -> cols ct2*16 + q4*4 + r, token = m16
    #pragma unroll
    for (int i = 0; i < 16; i++)
        #pragma unroll
        for (int r = 0; r < 4; r++) acc2[i][r] = 0.f;

    const int l1 = m16 + (((2 * q4) & 3) << 4);      // shfl src lanes
    const int l2 = m16 + (((2 * q4 + 1) & 3) << 4);
    const bool hi = q4 >= 2;
    const int kswz2 = (m16 & 6) << 2;                // w2 un-swizzle (shorts)

    #pragma unroll 1
    for (int c = 0; c < 32; ++c) {
        const int cur = c & 1;
        // own 4 staged loads for chunk c must have landed; barrier frees buf^1
        asm volatile("s_waitcnt vmcnt(0)" ::: "memory");
        __builtin_amdgcn_s_barrier();
        __builtin_amdgcn_sched_barrier(0);

        // ---- issue staging for chunk c+1 into the other buffer ----
        if (c + 1 < 32) {
            const unsigned short* s1 = w1s + (size_t)(c + 1) * 8192 + tid * 8;
            const unsigned short* s2 = w2s + (size_t)(c + 1) * 8192 + tid * 8;
            unsigned short* d1 = &Bs1[cur ^ 1][tid * 8];
            unsigned short* d2 = &Bs2[cur ^ 1][tid * 8];
            #pragma unroll
            for (int j = 0; j < 2; j++) {
                gload_lds16(s1 + j * 4096, d1 + j * 4096);
                gload_lds16(s2 + j * 4096, d2 + j * 4096);
            }
        }
        __builtin_amdgcn_sched_barrier(0);

        // ---- GEMM1 swapped: acc1[ct] = H^T[hidden ct*16+q4*4+r][token m16] ----
        f32x4 acc1[2];
        #pragma unroll
        for (int ct = 0; ct < 2; ct++)
            #pragma unroll
            for (int r = 0; r < 4; r++) acc1[ct][r] = 0.f;
        const unsigned short* b1base = &Bs1[cur][0];
        __builtin_amdgcn_s_setprio(1);
        #pragma unroll
        for (int ks = 0; ks < 8; ks++) {
            int kidx = (ks * 32 + q4 * 8) ^ ((m16 & 7) << 3);  // un-swizzle
            #pragma unroll
            for (int ct = 0; ct < 2; ct++) {
                bf16x8 wfr = *(const bf16x8*)(b1base + (ct * 16 + m16) * 256 + kidx);
                acc1[ct] = __builtin_amdgcn_mfma_f32_16x16x32_bf16(wfr, areg[ks], acc1[ct], 0, 0, 0);
            }
        }
        __builtin_amdgcn_s_setprio(0);

        // ---- bias + gelu -> packed bf16 (2 dwords per ct) ----
        union { ushort4 s; unsigned int u[2]; } pk[2];
        #pragma unroll
        for (int ct = 0; ct < 2; ct++) {
            float4 bb = *(const float4*)(b1F + c * 32 + ct * 16 + q4 * 4);
            pk[ct].s.x = f2bf(gelu_erf(acc1[ct][0] + bb.x));
            pk[ct].s.y = f2bf(gelu_erf(acc1[ct][1] + bb.y));
            pk[ct].s.z = f2bf(gelu_erf(acc1[ct][2] + bb.z));
            pk[ct].s.w = f2bf(gelu_erf(acc1[ct][3] + bb.w));
        }

        // ---- redistribute to GEMM2 B-frag: lane needs H[token m16][q4*8+u] ----
        unsigned int r0x = __shfl(pk[0].u[0], l1), r0y = __shfl(pk[0].u[1], l1);
        unsigned int r0z = __shfl(pk[0].u[0], l2), r0w = __shfl(pk[0].u[1], l2);
        unsigned int r1x = __shfl(pk[1].u[0], l1), r1y = __shfl(pk[1].u[1], l1);
        unsigned int r1z = __shfl(pk[1].u[0], l2), r1w = __shfl(pk[1].u[1], l2);
        union { bf16x8 v; unsigned int u[4]; } bfrag;
        bfrag.u[0] = hi ? r1x : r0x;
        bfrag.u[1] = hi ? r1y : r0y;
        bfrag.u[2] = hi ? r1z : r0z;
        bfrag.u[3] = hi ? r1w : r0w;

        // ---- GEMM2 swapped: A = w2 frags from LDS dbuf (swizzled) ----
        const unsigned short* b2base = &Bs2[cur][0];
        #pragma unroll
        for (int g = 0; g < 4; g++) {
            bf16x8 wf[4];
            #pragma unroll
            for (int j = 0; j < 4; j++)
                wf[j] = *(const bf16x8*)(b2base + ((g * 4 + j) * 16 + m16) * 32 + ((q4 * 8) ^ kswz2));
            __builtin_amdgcn_s_setprio(1);
            #pragma unroll
            for (int j = 0; j < 4; j++)
                acc2[g * 4 + j] = __builtin_amdgcn_mfma_f32_16x16x32_bf16(
                    wf[j], bfrag.v, acc2[g * 4 + j], 0, 0, 0);
            __builtin_amdgcn_s_setprio(0);
        }
    }

    // ---- epilogue: + b2 + residual (b64 read), vectorized store ----
    const size_t trow = (size_t)tok * 256;
    #pragma unroll
    for (int ct2 = 0; ct2 < 16; ct2++) {
        int col0 = ct2 * 16 + q4 * 4;
        float4 bb = *(const float4*)(b2F + col0);
        ushort4 rv = *(const ushort4*)(x2 + trow + col0);
        float v0 = acc2[ct2][0] + bb.x + bf2f(rv.x);
        float v1 = acc2[ct2][1] + bb.y + bf2f(rv.y);
        float v2 = acc2[ct2][2] + bb.z + bf2f(rv.z);
        float v3 = acc2[ct2][3] + bb.w + bf2f(rv.w);
        if (f) {
            float4 ov = {v0, v1, v2, v3};
            *(float4*)((float*)out + trow + col0) = ov;
        } else {
            ushort4 ov;
            ov.x = f2bf(v0); ov.y = f2bf(v1); ov.z = f2bf(v2); ov.w = f2bf(v3);
            *(ushort4*)((unsigned short*)out + trow + col0) = ov;
        }
    }
}

// ------------------------------- launcher ----------------------------------
extern "C" void kernel_launch(void* const* d_in, const int* in_sizes, int n_in,
                              void* d_out, int out_size, void* d_ws, size_t ws_size,
                              hipStream_t stream) {
    const void* x      = d_in[0];
    const void* qkv_w  = d_in[3];
    const void* proj_w = d_in[6];
    const void* w1     = d_in[10];
    const void* w2     = d_in[12];

    char* ws = (char*)d_ws;
    size_t off = 0;
    unsigned short* y = (unsigned short*)(ws + off);       // LN1 out; reused as attn out
    off += (size_t)NTOK * 256 * 2;
    size_t qkv_off = off;
    unsigned short* qkv = (unsigned short*)(ws + off);     // (NTOK,768) bf16
    off += (size_t)NTOK * 768 * 2;
    unsigned short* x2 = (unsigned short*)(ws + qkv_off);  // overlaps qkv (dead by then)
    unsigned short* o = y;                                 // overlaps y (dead after QKV GEMM)
    unsigned short* qkvWt = (unsigned short*)(ws + off); off += 768 * 256 * 2;
    unsigned short* projWt = (unsigned short*)(ws + off); off += 256 * 256 * 2;
    unsigned short* w1s = (unsigned short*)(ws + off); off += 1024 * 256 * 2;
    unsigned short* w2s = (unsigned short*)(ws + off); off += 256 * 1024 * 2;
    float* paramsF = (float*)(ws + off); off += NPARAM * 4;
    int* flag = (int*)(ws + off); off += 16;
    float* tbl = (float*)(ws + off); off += (size_t)TBL_ELEMS * 4;
    (void)ws_size; (void)in_sizes; (void)n_in; (void)out_size;

    detect_kernel<<<1, 64, 0, stream>>>((const unsigned short*)x, flag);
    convert_params_kernel<<<(NPARAM + 255) / 256, 256, 0, stream>>>(
        d_in[1], d_in[2], d_in[4], d_in[7], d_in[8], d_in[9], d_in[11], d_in[13],
        d_in[5], flag, paramsF);
    build_tbl_kernel<<<(TBL_ELEMS + 255) / 256, 256, 0, stream>>>(paramsF + 3328, tbl);
    transpose_any<<<(256 * 768 + 255) / 256, 256, 0, stream>>>(qkv_w, qkvWt, 256, 768, flag);
    transpose_any<<<(256 * 256 + 255) / 256, 256, 0, stream>>>(proj_w, projWt, 256, 256, flag);
    relayout_w1<<<(256 * 1024 + 255) / 256, 256, 0, stream>>>(w1, w1s, flag);
    relayout_w2<<<(1024 * 256 + 255) / 256, 256, 0, stream>>>(w2, w2s, flag);

    ln1_window_kernel<<<NTOK / 4, 256, 0, stream>>>(x, paramsF, y, flag);
    gemm_qkv_kernel<<<dim3(768 / 64, NTOK / 128), 256, 0, stream>>>(y, qkvWt, paramsF + 512, qkv);
    attn_mfma_kernel<<<4096, 256, 0, stream>>>(qkv, tbl, o);
    gemm_proj_kernel<<<dim3(256 / 64, NTOK / 128), 256, 0, stream>>>(
        o, projWt, paramsF + 1280, x, x2, flag);
    mlp_fused_v5<<<NTOK / 128, 512, 0, stream>>>(
        x2, paramsF + 1536, paramsF + 1792, w1s, paramsF + 2048, w2s, paramsF + 3072, d_out, flag);
}

// Round 5
// 1469.757 us; speedup vs baseline: 1.0198x; 1.0056x over previous
//
#include <hip/hip_runtime.h>
#include <math.h>

// ---------------------------------------------------------------------------
// Swin block: B=64 H=W=56 C=256 WIN=7 SHIFT=3 HEADS=8 HD=32.
// Input/output dtype (fp32 vs bf16) detected at runtime; bf16 MFMA pipeline.
// Round 8: MLP v6 — LDS-traffic-bound fix. 32x32x16 MFMA (2x FLOPs per
// operand byte) + 32 tokens/wave (256/block, 784 blocks) halves weight LDS
// reads per token; shfl_xor(32) H-exchange (conflict-free bpermute);
// conflict-free service-group LDS patterns throughout. attn/GEMMs unchanged.
// ---------------------------------------------------------------------------

typedef __attribute__((ext_vector_type(8))) short bf16x8;   // 8 bf16 = 4 VGPRs
typedef __attribute__((ext_vector_type(4))) float f32x4;
typedef __attribute__((ext_vector_type(16))) float f32x16;

#define NTOK 200704   // 64*56*56
#define NN   49
#define NPARAM 4680   // fp32 param block element count
#define TBL_ELEMS (4 * 8 * 49 * 64)

__device__ __forceinline__ float bf2f(unsigned short u) {
    union { unsigned int i; float f; } v; v.i = ((unsigned)u) << 16; return v.f;
}
__device__ __forceinline__ unsigned short f2bf(float f) {
    union { float fv; unsigned int i; } v; v.fv = f;
    return (unsigned short)((v.i + 0x7fffu + ((v.i >> 16) & 1u)) >> 16);  // RNE
}

// async global->LDS 16B (wave-uniform dest base + lane*16 pattern required)
__device__ __forceinline__ void gload_lds16(const unsigned short* g, unsigned short* l) {
    __builtin_amdgcn_global_load_lds(
        (const __attribute__((address_space(1))) unsigned int*)g,
        (__attribute__((address_space(3))) unsigned int*)l, 16, 0, 0);
}

// A&S 7.1.26 erf, |eps|<1.5e-7; gelu(v)=0.5v+0.5|v|*erf(|v|/sqrt2)*sgn-fold
__device__ __forceinline__ float gelu_erf(float v) {
    float av = fabsf(v);
    float x = av * 0.70710678118654752f;
    float t = __builtin_amdgcn_rcpf(fmaf(x, 0.3275911f, 1.0f));
    float p = fmaf(1.061405429f, t, -1.453152027f);
    p = fmaf(p, t, 1.421413741f);
    p = fmaf(p, t, -0.284496736f);
    p = fmaf(p, t, 0.254829592f);
    p = p * t;
    float ex = __builtin_amdgcn_exp2f(x * x * -1.4426950408889634f);
    float E = fmaf(-p, ex, 1.0f);          // erf(|v|/sqrt2)
    return fmaf(0.5f * av, E, 0.5f * v);
}

// ------------------------------ dtype detector -----------------------------
__global__ void detect_kernel(const unsigned short* __restrict__ xu, int* flag) {
    int ln = threadIdx.x;  // 64 threads
    int sane = 0;
    #pragma unroll
    for (int t = 0; t < 16; t++) {
        unsigned u = xu[(ln * 16 + t) * 2];
        unsigned e = (u >> 7) & 0xFF;
        sane += (e >= 0x60 && e <= 0x90) ? 1 : 0;
    }
    #pragma unroll
    for (int off = 32; off; off >>= 1) sane += __shfl_xor(sane, off);
    if (ln == 0) *flag = (sane < 614) ? 1 : 0;
}

__device__ __forceinline__ float ld_any(const void* p, int j, int f) {
    return f ? ((const float*)p)[j] : bf2f(((const unsigned short*)p)[j]);
}

// ------------------------ small params -> fp32 block -----------------------
__global__ void convert_params_kernel(
    const void* ln1_g, const void* ln1_b, const void* qkv_b, const void* proj_b,
    const void* ln2_g, const void* ln2_b, const void* b1, const void* b2,
    const void* rpb, const int* __restrict__ flag, float* __restrict__ dst) {
    int i = blockIdx.x * 256 + threadIdx.x;
    if (i >= NPARAM) return;
    int f = *flag;
    const void* src; int j;
    if      (i < 256)  { src = ln1_g;  j = i; }
    else if (i < 512)  { src = ln1_b;  j = i - 256; }
    else if (i < 1280) { src = qkv_b;  j = i - 512; }
    else if (i < 1536) { src = proj_b; j = i - 1280; }
    else if (i < 1792) { src = ln2_g;  j = i - 1536; }
    else if (i < 2048) { src = ln2_b;  j = i - 1792; }
    else if (i < 3072) { src = b1;     j = i - 2048; }
    else if (i < 3328) { src = b2;     j = i - 3072; }
    else               { src = rpb;    j = i - 3328; }
    dst[i] = ld_any(src, j, f);
}

// -------- combined bias+mask table: tbl[pat][head][q 49][k 64] f32 ---------
__global__ void build_tbl_kernel(const float* __restrict__ rpbF,
                                 float* __restrict__ tbl) {
    int idx = blockIdx.x * 256 + threadIdx.x;
    if (idx >= TBL_ELEMS) return;
    int k = idx & 63;
    int q = (idx >> 6) % 49;
    int h = ((idx >> 6) / 49) & 7;
    int pat = idx / (64 * 49 * 8);
    float v;
    if (k >= 49) {
        v = -1e30f;
    } else {
        int ir = q / 7, ic = q - ir * 7, jr = k / 7, jc = k - jr * 7;
        v = rpbF[((ir - jr + 6) * 13 + (ic - jc + 6)) * 8 + h];
        int rb = pat >> 1, cb = pat & 1;
        int ci = (rb ? (ir < 4 ? 3 : 6) : 0) + (cb ? (ic < 4 ? 1 : 2) : 0);
        int cj = (rb ? (jr < 4 ? 3 : 6) : 0) + (cb ? (jc < 4 ? 1 : 2) : 0);
        if (ci != cj) v -= 100.f;
    }
    tbl[idx] = v;
}

// --------------------- weight transpose (any dtype -> bf16) ----------------
// in: (K,N) row-major -> out: (N,K) row-major bf16
__global__ void transpose_any(const void* __restrict__ in,
                              unsigned short* __restrict__ out, int K, int N,
                              const int* __restrict__ flag) {
    int f = *flag;
    int idx = blockIdx.x * 256 + threadIdx.x;
    if (idx < K * N) {
        int k = idx / N, n = idx - k * N;
        out[n * K + k] = f2bf(ld_any(in, idx, f));
    }
}

// ---- w1 (256,1024) -> 32 chunks of [32 h-rows x 256 k], XOR-pre-swizzled ---
__global__ void relayout_w1(const void* __restrict__ in,
                            unsigned short* __restrict__ out,
                            const int* __restrict__ flag) {
    int f = *flag;
    int idx = blockIdx.x * 256 + threadIdx.x;  // over 256*1024, in elem (k,h)
    if (idx < 256 * 1024) {
        int k = idx >> 10, h = idx & 1023;
        int c = h >> 5, r = h & 31;
        int ks = k ^ ((r & 7) << 3);           // pre-swizzle within 256-short row
        out[c * 8192 + r * 256 + ks] = f2bf(ld_any(in, idx, f));
    }
}

// ------------- w2 (1024,256) -> k-chunk-major blocks (32 x [256n x 32k]) ---
// XOR-pre-swizzled: slot = kk ^ ((n&6)<<2) so ds_read_b128 of A-frags
// (8-lane service groups over consecutive n) hits 8 distinct 16B slots.
__global__ void relayout_w2(const void* __restrict__ in,
                            unsigned short* __restrict__ out,
                            const int* __restrict__ flag) {
    int f = *flag;
    int idx = blockIdx.x * 256 + threadIdx.x;  // over 1024*256
    if (idx < 1024 * 256) {
        int k = idx >> 8, n = idx & 255;
        int c = k >> 5, kk = k & 31;
        int slot = kk ^ ((n & 6) << 2);
        out[c * 8192 + n * 32 + slot] = f2bf(ld_any(in, idx, f));
    }
}

// ------------------------- LN1 + shift + window partition ------------------
__global__ __launch_bounds__(256) void ln1_window_kernel(
    const void* __restrict__ x, const float* __restrict__ paramsF,
    unsigned short* __restrict__ y, const int* __restrict__ flag) {
    int f = *flag;
    int wv = threadIdx.x >> 6, ln = threadIdx.x & 63;
    int tok = blockIdx.x * 4 + wv;
    float v0, v1, v2, v3;
    if (f) {
        float4 pv = *(const float4*)((const float*)x + (size_t)tok * 256 + ln * 4);
        v0 = pv.x; v1 = pv.y; v2 = pv.z; v3 = pv.w;
    } else {
        ushort4 pv = *(const ushort4*)((const unsigned short*)x + (size_t)tok * 256 + ln * 4);
        v0 = bf2f(pv.x); v1 = bf2f(pv.y); v2 = bf2f(pv.z); v3 = bf2f(pv.w);
    }
    float s = v0 + v1 + v2 + v3;
    float sq = v0 * v0 + v1 * v1 + v2 * v2 + v3 * v3;
    #pragma unroll
    for (int off = 32; off; off >>= 1) { s += __shfl_xor(s, off); sq += __shfl_xor(sq, off); }
    float mu = s * (1.f / 256.f);
    float rs = rsqrtf(fmaxf(sq * (1.f / 256.f) - mu * mu, 0.f) + 1e-5f);
    float4 gv = *(const float4*)(paramsF + ln * 4);        // ln1_g
    float4 bv = *(const float4*)(paramsF + 256 + ln * 4);  // ln1_b
    int bb = tok / 3136, hw = tok - bb * 3136;
    int h = hw / 56, w = hw - h * 56;
    int hp = h - 3; hp += (hp < 0) ? 56 : 0;
    int wp = w - 3; wp += (wp < 0) ? 56 : 0;
    int win = (hp / 7) * 8 + (wp / 7);
    int n = (hp % 7) * 7 + (wp % 7);
    size_t drow = ((size_t)bb * 64 + win) * NN + n;
    ushort4 o;
    o.x = f2bf((v0 - mu) * rs * gv.x + bv.x);
    o.y = f2bf((v1 - mu) * rs * gv.y + bv.y);
    o.z = f2bf((v2 - mu) * rs * gv.z + bv.z);
    o.w = f2bf((v3 - mu) * rs * gv.w + bv.w);
    *(ushort4*)(y + drow * 256 + ln * 4) = o;
}

// ------------------------------ GEMM core (K=256) --------------------------
__device__ __forceinline__ void gemm_core_k256(
    const unsigned short* __restrict__ A, const unsigned short* __restrict__ Bt,
    int rowBase, int colBase, unsigned short* As, unsigned short* Bs, f32x4 acc[2][4]) {
    const int tid = threadIdx.x;
    const int wv = tid >> 6, ln = tid & 63;
    const int m16 = ln & 15, q4 = ln >> 4;
    const int ar = tid >> 1, ah = (tid & 1) * 32;
    const int br = tid >> 2, bp = (tid & 3) * 16;
    for (int kb = 0; kb < 256; kb += 64) {
        const unsigned short* ag = A + (size_t)(rowBase + ar) * 256 + kb + ah;
        unsigned short* asd = As + ar * 72 + ah;
        #pragma unroll
        for (int i = 0; i < 4; i++)
            *(bf16x8*)(asd + i * 8) = *(const bf16x8*)(ag + i * 8);
        const unsigned short* bg = Bt + (size_t)(colBase + br) * 256 + kb + bp;
        unsigned short* bsd = Bs + br * 72 + bp;
        #pragma unroll
        for (int i = 0; i < 2; i++)
            *(bf16x8*)(bsd + i * 8) = *(const bf16x8*)(bg + i * 8);
        __syncthreads();
        #pragma unroll
        for (int ks = 0; ks < 64; ks += 32) {
            bf16x8 af[2], bfr[4];
            #pragma unroll
            for (int rt = 0; rt < 2; rt++)
                af[rt] = *(const bf16x8*)(As + (wv * 32 + rt * 16 + m16) * 72 + ks + q4 * 8);
            #pragma unroll
            for (int ct = 0; ct < 4; ct++)
                bfr[ct] = *(const bf16x8*)(Bs + (ct * 16 + m16) * 72 + ks + q4 * 8);
            #pragma unroll
            for (int rt = 0; rt < 2; rt++)
                #pragma unroll
                for (int ct = 0; ct < 4; ct++)
                    acc[rt][ct] = __builtin_amdgcn_mfma_f32_16x16x32_bf16(
                        af[rt], bfr[ct], acc[rt][ct], 0, 0, 0);
        }
        __syncthreads();
    }
}

// ------------------------------- GEMM: QKV ---------------------------------
__global__ __launch_bounds__(256) void gemm_qkv_kernel(
    const unsigned short* __restrict__ A, const unsigned short* __restrict__ Bt,
    const float* __restrict__ bias,  // qkv_b fp32 (768)
    unsigned short* __restrict__ out) {
    __shared__ unsigned short As[128 * 72];
    __shared__ unsigned short Bs[64 * 72];
    const int ln = threadIdx.x & 63, wv = threadIdx.x >> 6;
    const int m16 = ln & 15, q4 = ln >> 4;
    const int rowBase = blockIdx.y * 128, colBase = blockIdx.x * 64;
    f32x4 acc[2][4];
    #pragma unroll
    for (int i = 0; i < 2; i++)
        #pragma unroll
        for (int j = 0; j < 4; j++)
            #pragma unroll
            for (int r = 0; r < 4; r++) acc[i][j][r] = 0.f;
    gemm_core_k256(A, Bt, rowBase, colBase, As, Bs, acc);
    #pragma unroll
    for (int rt = 0; rt < 2; rt++)
        #pragma unroll
        for (int ct = 0; ct < 4; ct++) {
            int col = colBase + ct * 16 + m16;
            float bs = bias[col];
            float scale = (col < 256) ? 0.17677669529663689f : 1.0f;  // q * HD^-0.5
            #pragma unroll
            for (int r = 0; r < 4; r++) {
                int row = rowBase + wv * 32 + rt * 16 + q4 * 4 + r;
                out[(size_t)row * 768 + col] = f2bf((acc[rt][ct][r] + bs) * scale);
            }
        }
}

// ------------------------- GEMM: proj + scatter + residual -----------------
__global__ __launch_bounds__(256) void gemm_proj_kernel(
    const unsigned short* __restrict__ A, const unsigned short* __restrict__ Bt,
    const float* __restrict__ bias,  // proj_b fp32
    const void* __restrict__ xin,    // x natural order (flag dtype)
    unsigned short* __restrict__ x2, const int* __restrict__ flag) {
    __shared__ unsigned short As[128 * 72];
    __shared__ unsigned short Bs[64 * 72];
    const int f = *flag;
    const int ln = threadIdx.x & 63, wv = threadIdx.x >> 6;
    const int m16 = ln & 15, q4 = ln >> 4;
    const int rowBase = blockIdx.y * 128, colBase = blockIdx.x * 64;
    f32x4 acc[2][4];
    #pragma unroll
    for (int i = 0; i < 2; i++)
        #pragma unroll
        for (int j = 0; j < 4; j++)
            #pragma unroll
            for (int r = 0; r < 4; r++) acc[i][j][r] = 0.f;
    gemm_core_k256(A, Bt, rowBase, colBase, As, Bs, acc);
    #pragma unroll
    for (int rt = 0; rt < 2; rt++)
        #pragma unroll
        for (int r = 0; r < 4; r++) {
            int row = rowBase + wv * 32 + rt * 16 + q4 * 4 + r;  // window-order token
            int win = row / NN, n = row - win * NN;
            int bb = win >> 6, wl = win & 63;
            int i7 = n / 7, j7 = n - i7 * 7;
            int hp = (wl >> 3) * 7 + i7 + 3; if (hp >= 56) hp -= 56;  // un-shift
            int wp = (wl & 7) * 7 + j7 + 3;  if (wp >= 56) wp -= 56;
            size_t drow = ((size_t)bb * 3136 + hp * 56 + wp) * 256;
            #pragma unroll
            for (int ct = 0; ct < 4; ct++) {
                int col = colBase + ct * 16 + m16;
                float v = acc[rt][ct][r] + bias[col] + ld_any(xin, drow + col, f);
                x2[drow + col] = f2bf(v);
            }
        }
}

// --------------------------- attention (MFMA) ------------------------------
__global__ __launch_bounds__(256) void attn_mfma_kernel(
    const unsigned short* __restrict__ qkv,  // (NTOK,768): [q|k|v] x head x d
    const float* __restrict__ tbl,           // [4][8][49][64] f32
    unsigned short* __restrict__ o) {        // (NTOK,256) window order
    __shared__ __align__(16) unsigned short Vt[256 * 72];   // [d 256][tok 72]
    __shared__ __align__(16) unsigned short Ps[4][64 * 72]; // per-wave [q 64][k 72]
    const int tid = threadIdx.x;
    const int wv = tid >> 6, ln = tid & 63;
    const int m16 = ln & 15, q4 = ln >> 4;
    const int win = blockIdx.x;
    const size_t wbase = (size_t)win * 49 * 768;

    // ---- build Vt: all heads, tok-contiguous writes (conflict-free) ----
    #pragma unroll
    for (int i = 0; i < 8; i++) {
        int idx = i * 256 + tid;             // ch = idx>>6 (0..31), tok = idx&63
        int ch = idx >> 6, tok = idx & 63;
        if (tok < 49) {
            bf16x8 v = *(const bf16x8*)(qkv + wbase + (size_t)tok * 768 + 512 + ch * 8);
            #pragma unroll
            for (int u = 0; u < 8; u++)
                Vt[(ch * 8 + u) * 72 + tok] = (unsigned short)v[u];
        }
    }
    // zero pad columns 49..71 of row tid (P=0 there anyway; avoid 0*NaN)
    #pragma unroll
    for (int u = 0; u < 23; u++) Vt[tid * 72 + 49 + u] = 0;

    const int wl = win & 63;
    const int pat = (((wl >> 3) == 7) ? 2 : 0) + (((wl & 7) == 7) ? 1 : 0);
    __syncthreads();

    unsigned short* Pw = &Ps[wv][0];
    for (int hh = 0; hh < 2; hh++) {
        const int h = wv * 2 + hh;
        // ---- QK^T swapped: acc[kt][qt] = S^T tile (key row, query col) ----
        bf16x8 kf[4], qf[4];
        #pragma unroll
        for (int t = 0; t < 4; t++) {
            size_t rrow = wbase + (size_t)(t * 16 + m16) * 768 + h * 32 + q4 * 8;
            qf[t] = *(const bf16x8*)(qkv + rrow);
            kf[t] = *(const bf16x8*)(qkv + rrow + 256);
        }
        f32x4 acc[4][4];
        #pragma unroll
        for (int kt = 0; kt < 4; kt++)
            #pragma unroll
            for (int qt = 0; qt < 4; qt++) {
                #pragma unroll
                for (int r = 0; r < 4; r++) acc[kt][qt][r] = 0.f;
                acc[kt][qt] = __builtin_amdgcn_mfma_f32_16x16x32_bf16(
                    kf[kt], qf[qt], acc[kt][qt], 0, 0, 0);
            }

        // ---- softmax per query column (qt, m16); keys lane-local ----
        const float* tb = tbl + ((size_t)(pat * 8 + h) * 49) * 64;
        #pragma unroll
        for (int qt = 0; qt < 4; qt++) {
            int q = qt * 16 + m16;
            int qc = q < 49 ? q : 48;
            float s[4][4];
            float mx = -3e38f;
            #pragma unroll
            for (int kt = 0; kt < 4; kt++) {
                float4 tv = *(const float4*)(tb + qc * 64 + kt * 16 + q4 * 4);
                s[kt][0] = acc[kt][qt][0] + tv.x;
                s[kt][1] = acc[kt][qt][1] + tv.y;
                s[kt][2] = acc[kt][qt][2] + tv.z;
                s[kt][3] = acc[kt][qt][3] + tv.w;
                #pragma unroll
                for (int r = 0; r < 4; r++) mx = fmaxf(mx, s[kt][r]);
            }
            mx = fmaxf(mx, __shfl_xor(mx, 16));
            mx = fmaxf(mx, __shfl_xor(mx, 32));
            float sum = 0.f;
            #pragma unroll
            for (int kt = 0; kt < 4; kt++)
                #pragma unroll
                for (int r = 0; r < 4; r++) {
                    float e = __expf(s[kt][r] - mx);
                    s[kt][r] = e; sum += e;
                }
            sum += __shfl_xor(sum, 16);
            sum += __shfl_xor(sum, 32);
            float inv = 1.f / sum;
            #pragma unroll
            for (int kt = 0; kt < 4; kt++) {
                ushort4 p4;
                p4.x = f2bf(s[kt][0] * inv);
                p4.y = f2bf(s[kt][1] * inv);
                p4.z = f2bf(s[kt][2] * inv);
                p4.w = f2bf(s[kt][3] * inv);
                *(ushort4*)(Pw + q * 72 + kt * 16 + q4 * 4) = p4;
            }
        }

        // ---- PV: O[q][d] = P·V, A=Ps rows, B=Vt rows ----
        f32x4 po[4][2];
        #pragma unroll
        for (int mt = 0; mt < 4; mt++)
            #pragma unroll
            for (int nt = 0; nt < 2; nt++)
                #pragma unroll
                for (int r = 0; r < 4; r++) po[mt][nt][r] = 0.f;
        #pragma unroll
        for (int kstep = 0; kstep < 2; kstep++) {
            bf16x8 pa[4], vb[2];
            #pragma unroll
            for (int mt = 0; mt < 4; mt++)
                pa[mt] = *(const bf16x8*)(Pw + (mt * 16 + m16) * 72 + kstep * 32 + q4 * 8);
            #pragma unroll
            for (int nt = 0; nt < 2; nt++)
                vb[nt] = *(const bf16x8*)(Vt + (h * 32 + nt * 16 + m16) * 72 + kstep * 32 + q4 * 8);
            #pragma unroll
            for (int mt = 0; mt < 4; mt++)
                #pragma unroll
                for (int nt = 0; nt < 2; nt++)
                    po[mt][nt] = __builtin_amdgcn_mfma_f32_16x16x32_bf16(
                        pa[mt], vb[nt], po[mt][nt], 0, 0, 0);
        }

        // ---- store O (rows q<49); 16 lanes write 32B contiguous ----
        #pragma unroll
        for (int mt = 0; mt < 4; mt++)
            #pragma unroll
            for (int r = 0; r < 4; r++) {
                int q = mt * 16 + q4 * 4 + r;
                if (q < 49) {
                    size_t orow = ((size_t)win * 49 + q) * 256 + h * 32;
                    o[orow + m16]      = f2bf(po[mt][0][r]);
                    o[orow + 16 + m16] = f2bf(po[mt][1][r]);
                }
            }
    }
}

// ---------------- fused LN2 + MLP + residual, v6 (32x32 MFMA) --------------
// 256 tokens/block (512 thr, 8 waves); wave owns 32 tokens end-to-end.
// Per 32-hidden chunk: GEMM1 swapped 32x32x16 (A=w1 LDS dbuf, B=LN2'd x in
// regs) -> gelu in regs -> 8x shfl_xor(32) exchange -> GEMM2 swapped
// 32x32x16 (A=w2 LDS dbuf) -> acc2[8] f32x16 (out^T). One barrier/chunk.
__global__ __launch_bounds__(512, 2) void mlp_fused_v6(
    const unsigned short* __restrict__ x2,
    const float* __restrict__ g2F, const float* __restrict__ b2lnF,
    const unsigned short* __restrict__ w1s,  // 32 chunks [32r x 256k] swizzled
    const float* __restrict__ b1F,
    const unsigned short* __restrict__ w2s,  // 32 chunks [256n x 32k] swizzled
    const float* __restrict__ b2F,
    void* __restrict__ out, const int* __restrict__ flag) {
    __shared__ __align__(16) unsigned short Bs1[2][32 * 256];  // 2 x 16KB
    __shared__ __align__(16) unsigned short Bs2[2][256 * 32];  // 2 x 16KB
    const int f = *flag;
    const int tid = threadIdx.x;             // 0..511
    const int wv = tid >> 6, ln = tid & 63;
    const int t32 = ln & 31, hi = ln >> 5;   // token-in-wave / k-half
    const int tok = blockIdx.x * 256 + wv * 32 + t32;

    // ---- issue chunk-0 staging first (overlaps LN2 below) ----
    {
        const unsigned short* s1 = w1s + tid * 8;
        const unsigned short* s2 = w2s + tid * 8;
        gload_lds16(s1,        &Bs1[0][tid * 8]);
        gload_lds16(s1 + 4096, &Bs1[0][tid * 8 + 4096]);
        gload_lds16(s2,        &Bs2[0][tid * 8]);
        gload_lds16(s2 + 4096, &Bs2[0][tid * 8 + 4096]);
    }

    // ---- load x2 row-half + LN2 -> areg[16] (GEMM1 B-frags, k=ks*16+hi*8) --
    bf16x8 areg[16];
    {
        const unsigned short* xr = x2 + (size_t)tok * 256 + hi * 8;
        #pragma unroll
        for (int ks = 0; ks < 16; ks++) areg[ks] = *(const bf16x8*)(xr + ks * 16);
        float s = 0.f, sq = 0.f;
        #pragma unroll
        for (int ks = 0; ks < 16; ks++)
            #pragma unroll
            for (int u = 0; u < 8; u++) {
                float v = bf2f((unsigned short)areg[ks][u]);
                s += v; sq += v * v;
            }
        s += __shfl_xor(s, 32); sq += __shfl_xor(sq, 32);
        float mu = s * (1.f / 256.f);
        float rs = rsqrtf(fmaxf(sq * (1.f / 256.f) - mu * mu, 0.f) + 1e-5f);
        #pragma unroll
        for (int ks = 0; ks < 16; ks++) {
            const int kb = ks * 16 + hi * 8;
            float4 ga = *(const float4*)(g2F + kb);
            float4 gb = *(const float4*)(g2F + kb + 4);
            float4 ba = *(const float4*)(b2lnF + kb);
            float4 bb = *(const float4*)(b2lnF + kb + 4);
            float g[8] = {ga.x, ga.y, ga.z, ga.w, gb.x, gb.y, gb.z, gb.w};
            float b[8] = {ba.x, ba.y, ba.z, ba.w, bb.x, bb.y, bb.z, bb.w};
            #pragma unroll
            for (int u = 0; u < 8; u++) {
                float v = (bf2f((unsigned short)areg[ks][u]) - mu) * rs * g[u] + b[u];
                areg[ks][u] = (short)f2bf(v);
            }
        }
    }

    f32x16 acc2[8];   // out^T: acc2[g] -> token t32, cols g*32+(r&3)+8(r>>2)+4hi
    #pragma unroll
    for (int g = 0; g < 8; g++)
        #pragma unroll
        for (int r = 0; r < 16; r++) acc2[g][r] = 0.f;

    const int rswz = (t32 & 7) << 3;                 // w1 un-swizzle (shorts)
    const int csw = ((t32 >> 1) & 3) << 3;           // w2 un-swizzle (shorts)

    #pragma unroll 1
    for (int c = 0; c < 32; ++c) {
        const int cur = c & 1;
        asm volatile("s_waitcnt vmcnt(0)" ::: "memory");
        __builtin_amdgcn_s_barrier();
        __builtin_amdgcn_sched_barrier(0);

        // ---- issue staging for chunk c+1 into the other buffer ----
        if (c + 1 < 32) {
            const unsigned short* s1 = w1s + (size_t)(c + 1) * 8192 + tid * 8;
            const unsigned short* s2 = w2s + (size_t)(c + 1) * 8192 + tid * 8;
            unsigned short* d1 = &Bs1[cur ^ 1][tid * 8];
            unsigned short* d2 = &Bs2[cur ^ 1][tid * 8];
            gload_lds16(s1,        d1);
            gload_lds16(s1 + 4096, d1 + 4096);
            gload_lds16(s2,        d2);
            gload_lds16(s2 + 4096, d2 + 4096);
        }
        __builtin_amdgcn_sched_barrier(0);

        // ---- GEMM1 swapped 32x32: acc1 = H^T tile (hidden rows, token cols)
        f32x16 acc1;
        #pragma unroll
        for (int r = 0; r < 16; r++) acc1[r] = 0.f;
        const unsigned short* b1b = &Bs1[cur][0];
        __builtin_amdgcn_s_setprio(1);
        #pragma unroll
        for (int ks = 0; ks < 16; ks++) {
            bf16x8 wfr = *(const bf16x8*)(b1b + t32 * 256 + ((ks * 16 + hi * 8) ^ rswz));
            acc1 = __builtin_amdgcn_mfma_f32_32x32x16_bf16(wfr, areg[ks], acc1, 0, 0, 0);
        }
        __builtin_amdgcn_s_setprio(0);

        // ---- bias + gelu -> 8 packed dwords (hidden pairs) ----
        // acc1 reg r: hidden = (r&3) + 8*(r>>2) + 4*hi  (token = t32)
        unsigned int d[8];
        #pragma unroll
        for (int G = 0; G < 4; G++) {
            float4 bb = *(const float4*)(b1F + c * 32 + G * 8 + hi * 4);
            float g0 = gelu_erf(acc1[G * 4 + 0] + bb.x);
            float g1 = gelu_erf(acc1[G * 4 + 1] + bb.y);
            float g2 = gelu_erf(acc1[G * 4 + 2] + bb.z);
            float g3 = gelu_erf(acc1[G * 4 + 3] + bb.w);
            d[G * 2]     = (unsigned)f2bf(g0) | ((unsigned)f2bf(g1) << 16);
            d[G * 2 + 1] = (unsigned)f2bf(g2) | ((unsigned)f2bf(g3) << 16);
        }

        // ---- exchange halves with lane^32 -> GEMM2 B-frags (k=hidden) ----
        unsigned int x0 = __shfl_xor(d[0], 32), x1 = __shfl_xor(d[1], 32);
        unsigned int x2e = __shfl_xor(d[2], 32), x3 = __shfl_xor(d[3], 32);
        unsigned int x4 = __shfl_xor(d[4], 32), x5 = __shfl_xor(d[5], 32);
        unsigned int x6 = __shfl_xor(d[6], 32), x7 = __shfl_xor(d[7], 32);
        union { bf16x8 v; unsigned int u[4]; } h0, h1;
        h0.u[0] = hi ? x2e  : d[0];
        h0.u[1] = hi ? x3   : d[1];
        h0.u[2] = hi ? d[2] : x0;
        h0.u[3] = hi ? d[3] : x1;
        h1.u[0] = hi ? x6   : d[4];
        h1.u[1] = hi ? x7   : d[5];
        h1.u[2] = hi ? d[6] : x4;
        h1.u[3] = hi ? d[7] : x5;

        // ---- GEMM2 swapped 32x32: A = w2 frags (LDS, swizzled), K=32 ----
        const unsigned short* b2b = &Bs2[cur][0];
        #pragma unroll
        for (int g = 0; g < 8; g++) {
            bf16x8 w0 = *(const bf16x8*)(b2b + (g * 32 + t32) * 32 + ((hi * 8) ^ csw));
            bf16x8 w1f = *(const bf16x8*)(b2b + (g * 32 + t32) * 32 + ((16 + hi * 8) ^ csw));
            __builtin_amdgcn_s_setprio(1);
            acc2[g] = __builtin_amdgcn_mfma_f32_32x32x16_bf16(w0, h0.v, acc2[g], 0, 0, 0);
            acc2[g] = __builtin_amdgcn_mfma_f32_32x32x16_bf16(w1f, h1.v, acc2[g], 0, 0, 0);
            __builtin_amdgcn_s_setprio(0);
        }
    }

    // ---- epilogue: + b2 + residual, vectorized store ----
    const size_t trow = (size_t)tok * 256;
    #pragma unroll
    for (int g = 0; g < 8; g++)
        #pragma unroll
        for (int G = 0; G < 4; G++) {
            int col0 = g * 32 + G * 8 + hi * 4;
            float4 bb = *(const float4*)(b2F + col0);
            ushort4 rv = *(const ushort4*)(x2 + trow + col0);
            float v0 = acc2[g][G * 4 + 0] + bb.x + bf2f(rv.x);
            float v1 = acc2[g][G * 4 + 1] + bb.y + bf2f(rv.y);
            float v2 = acc2[g][G * 4 + 2] + bb.z + bf2f(rv.z);
            float v3 = acc2[g][G * 4 + 3] + bb.w + bf2f(rv.w);
            if (f) {
                float4 ov = {v0, v1, v2, v3};
                *(float4*)((float*)out + trow + col0) = ov;
            } else {
                ushort4 ov;
                ov.x = f2bf(v0); ov.y = f2bf(v1); ov.z = f2bf(v2); ov.w = f2bf(v3);
                *(ushort4*)((unsigned short*)out + trow + col0) = ov;
            }
        }
}

// ------------------------------- launcher ----------------------------------
extern "C" void kernel_launch(void* const* d_in, const int* in_sizes, int n_in,
                              void* d_out, int out_size, void* d_ws, size_t ws_size,
                              hipStream_t stream) {
    const void* x      = d_in[0];
    const void* qkv_w  = d_in[3];
    const void* proj_w = d_in[6];
    const void* w1     = d_in[10];
    const void* w2     = d_in[12];

    char* ws = (char*)d_ws;
    size_t off = 0;
    unsigned short* y = (unsigned short*)(ws + off);       // LN1 out; reused as attn out
    off += (size_t)NTOK * 256 * 2;
    size_t qkv_off = off;
    unsigned short* qkv = (unsigned short*)(ws + off);     // (NTOK,768) bf16
    off += (size_t)NTOK * 768 * 2;
    unsigned short* x2 = (unsigned short*)(ws + qkv_off);  // overlaps qkv (dead by then)
    unsigned short* o = y;                                 // overlaps y (dead after QKV GEMM)
    unsigned short* qkvWt = (unsigned short*)(ws + off); off += 768 * 256 * 2;
    unsigned short* projWt = (unsigned short*)(ws + off); off += 256 * 256 * 2;
    unsigned short* w1s = (unsigned short*)(ws + off); off += 1024 * 256 * 2;
    unsigned short* w2s = (unsigned short*)(ws + off); off += 256 * 1024 * 2;
    float* paramsF = (float*)(ws + off); off += NPARAM * 4;
    int* flag = (int*)(ws + off); off += 16;
    float* tbl = (float*)(ws + off); off += (size_t)TBL_ELEMS * 4;
    (void)ws_size; (void)in_sizes; (void)n_in; (void)out_size;

    detect_kernel<<<1, 64, 0, stream>>>((const unsigned short*)x, flag);
    convert_params_kernel<<<(NPARAM + 255) / 256, 256, 0, stream>>>(
        d_in[1], d_in[2], d_in[4], d_in[7], d_in[8], d_in[9], d_in[11], d_in[13],
        d_in[5], flag, paramsF);
    build_tbl_kernel<<<(TBL_ELEMS + 255) / 256, 256, 0, stream>>>(paramsF + 3328, tbl);
    transpose_any<<<(256 * 768 + 255) / 256, 256, 0, stream>>>(qkv_w, qkvWt, 256, 768, flag);
    transpose_any<<<(256 * 256 + 255) / 256, 256, 0, stream>>>(proj_w, projWt, 256, 256, flag);
    relayout_w1<<<(256 * 1024 + 255) / 256, 256, 0, stream>>>(w1, w1s, flag);
    relayout_w2<<<(1024 * 256 + 255) / 256, 256, 0, stream>>>(w2, w2s, flag);

    ln1_window_kernel<<<NTOK / 4, 256, 0, stream>>>(x, paramsF, y, flag);
    gemm_qkv_kernel<<<dim3(768 / 64, NTOK / 128), 256, 0, stream>>>(y, qkvWt, paramsF + 512, qkv);
    attn_mfma_kernel<<<4096, 256, 0, stream>>>(qkv, tbl, o);
    gemm_proj_kernel<<<dim3(256 / 64, NTOK / 128), 256, 0, stream>>>(
        o, projWt, paramsF + 1280, x, x2, flag);
    mlp_fused_v6<<<NTOK / 256, 512, 0, stream>>>(
        x2, paramsF + 1536, paramsF + 1792, w1s, paramsF + 2048, w2s, paramsF + 3072, d_out, flag);
}